// Round 1
// baseline (1665.233 us; speedup 1.0000x reference)
//
#include <hip/hip_runtime.h>
#include <hip/hip_bf16.h>
#include <math.h>

#define B_   32
#define N_   512
#define D_   256
#define H_   8
#define DH_  32
#define L_   2
#define ROWS (B_ * N_)          // 16384
#define EPS_ 1e-5f

// ---------------------------------------------------------------------------
// Generic f32 GEMM:  C[m,n] = sum_k A[m,k] * W[n,k] + bias[n]   (NT layout)
// 64x64 tile, BK=32, 256 threads, 4x4 microtile. ACT: 0=none, 1=relu.
// ---------------------------------------------------------------------------
template<int ACT>
__global__ __launch_bounds__(256) void gemm_nt(const float* __restrict__ A,
                                               const float* __restrict__ W,
                                               const float* __restrict__ bias,
                                               float* __restrict__ C,
                                               int M, int Nn, int K)
{
    __shared__ float As[32][68];   // [k][m], pad 4 for float4-aligned rows
    __shared__ float Bs[32][68];   // [k][n]
    const int t  = threadIdx.x;
    const int tx = t & 15, ty = t >> 4;
    const int m0 = blockIdx.x * 64;
    const int n0 = blockIdx.y * 64;
    const int krow = t >> 3;        // 0..31
    const int k4   = (t & 7) * 4;   // 0,4,...,28
    float acc[4][4] = {};

    for (int kb = 0; kb < K; kb += 32) {
        #pragma unroll
        for (int rr = 0; rr < 64; rr += 32) {
            float4 a = *(const float4*)&A[(size_t)(m0 + krow + rr) * K + kb + k4];
            As[k4 + 0][krow + rr] = a.x; As[k4 + 1][krow + rr] = a.y;
            As[k4 + 2][krow + rr] = a.z; As[k4 + 3][krow + rr] = a.w;
            float4 b = *(const float4*)&W[(size_t)(n0 + krow + rr) * K + kb + k4];
            Bs[k4 + 0][krow + rr] = b.x; Bs[k4 + 1][krow + rr] = b.y;
            Bs[k4 + 2][krow + rr] = b.z; Bs[k4 + 3][krow + rr] = b.w;
        }
        __syncthreads();
        #pragma unroll
        for (int k = 0; k < 32; k++) {
            float4 a4 = *(const float4*)&As[k][ty * 4];
            float4 b4 = *(const float4*)&Bs[k][tx * 4];
            float av[4] = {a4.x, a4.y, a4.z, a4.w};
            float bv[4] = {b4.x, b4.y, b4.z, b4.w};
            #pragma unroll
            for (int i = 0; i < 4; i++)
                #pragma unroll
                for (int j = 0; j < 4; j++)
                    acc[i][j] = fmaf(av[i], bv[j], acc[i][j]);
        }
        __syncthreads();
    }

    #pragma unroll
    for (int i = 0; i < 4; i++) {
        const int m = m0 + ty * 4 + i;
        float4 o;
        float* op = &o.x;
        #pragma unroll
        for (int j = 0; j < 4; j++) {
            float v = acc[i][j] + bias[n0 + tx * 4 + j];
            if (ACT == 1) v = fmaxf(v, 0.f);
            op[j] = v;
        }
        *(float4*)&C[(size_t)m * Nn + n0 + tx * 4] = o;
    }
}

// ---------------------------------------------------------------------------
// BatchNorm over dim0 (16384 rows x 256 cols), two-stage deterministic.
// ---------------------------------------------------------------------------
__global__ __launch_bounds__(256) void bn_partial(const float* __restrict__ Y,
                                                  float* __restrict__ part)
{
    const int t = threadIdx.x, blk = blockIdx.x;   // 64 blocks x 256 rows
    float s = 0.f, sq = 0.f;
    const float* p = Y + (size_t)blk * 256 * 256 + t;
    for (int r = 0; r < 256; r++) {
        float v = p[(size_t)r * 256];
        s += v; sq += v * v;
    }
    part[blk * 512 + t]       = s;
    part[blk * 512 + 256 + t] = sq;
}

__global__ __launch_bounds__(256) void bn_finalize(const float* __restrict__ part,
                                                   const float* __restrict__ g,
                                                   const float* __restrict__ b,
                                                   float* __restrict__ sc)
{
    const int t = threadIdx.x;
    float s = 0.f, sq = 0.f;
    for (int i = 0; i < 64; i++) { s += part[i * 512 + t]; sq += part[i * 512 + 256 + t]; }
    const float mean = s * (1.f / (float)ROWS);
    const float var  = sq * (1.f / (float)ROWS) - mean * mean;
    const float k    = g[t] * rsqrtf(var + EPS_);
    sc[t]       = k;
    sc[256 + t] = b[t] - mean * k;
}

__global__ __launch_bounds__(256) void bn_apply_leaky(const float* __restrict__ Y,
                                                      const float* __restrict__ sc,
                                                      float* __restrict__ O)
{
    const int idx = blockIdx.x * 256 + threadIdx.x;      // float4 index
    const int c4  = (idx & 63) * 4;
    const float4 v  = *(const float4*)&Y[(size_t)idx * 4];
    const float4 k  = *(const float4*)&sc[c4];
    const float4 sh = *(const float4*)&sc[256 + c4];
    float4 o;
    o.x = fmaf(v.x, k.x, sh.x); o.x = o.x >= 0.f ? o.x : 0.01f * o.x;
    o.y = fmaf(v.y, k.y, sh.y); o.y = o.y >= 0.f ? o.y : 0.01f * o.y;
    o.z = fmaf(v.z, k.z, sh.z); o.z = o.z >= 0.f ? o.z : 0.01f * o.z;
    o.w = fmaf(v.w, k.w, sh.w); o.w = o.w >= 0.f ? o.w : 0.01f * o.w;
    *(float4*)&O[(size_t)idx * 4] = o;
}

// ---------------------------------------------------------------------------
// Degree: deg[b,j] = sum_i (adj[b,i,j] != 0); then h[b,j,:] += deg_emb[deg]
// ---------------------------------------------------------------------------
__global__ __launch_bounds__(256) void deg_kernel(const int* __restrict__ adj,
                                                  int* __restrict__ deg)
{
    const int b = blockIdx.x;
    const int j = blockIdx.y * 256 + threadIdx.x;
    const int* p = adj + (size_t)b * N_ * N_ + j;
    int c = 0;
    for (int i = 0; i < N_; i++) c += (p[(size_t)i * N_] != 0);
    deg[b * N_ + j] = c;
}

__global__ __launch_bounds__(256) void deg_add(const int* __restrict__ deg,
                                               const float* __restrict__ emb,
                                               float* __restrict__ h)
{
    const int idx = blockIdx.x * 256 + threadIdx.x;   // float4 index
    const int row = idx >> 6;
    const int c4  = (idx & 63) * 4;
    const int d   = deg[row];
    const float4 e = *(const float4*)&emb[(size_t)d * 256 + c4];
    float4 v = *(float4*)&h[(size_t)idx * 4];
    v.x += e.x; v.y += e.y; v.z += e.z; v.w += e.w;
    *(float4*)&h[(size_t)idx * 4] = v;
}

// ---------------------------------------------------------------------------
// Residual + LayerNorm (row of 256), one wave per row, in-place into h.
// ---------------------------------------------------------------------------
__global__ __launch_bounds__(256) void add_ln(float* __restrict__ h,
                                              const float* __restrict__ p,
                                              const float* __restrict__ g,
                                              const float* __restrict__ be)
{
    const int wv = threadIdx.x >> 6, ln = threadIdx.x & 63;
    const size_t row  = (size_t)blockIdx.x * 4 + wv;
    const size_t base = row * 256 + ln * 4;
    const float4 a = *(const float4*)&h[base];
    const float4 q = *(const float4*)&p[base];
    const float v0 = a.x + q.x, v1 = a.y + q.y, v2 = a.z + q.z, v3 = a.w + q.w;
    float s  = v0 + v1 + v2 + v3;
    float sq = v0 * v0 + v1 * v1 + v2 * v2 + v3 * v3;
    #pragma unroll
    for (int m = 1; m < 64; m <<= 1) {
        s  += __shfl_xor(s,  m, 64);
        sq += __shfl_xor(sq, m, 64);
    }
    const float mean = s * (1.f / 256.f);
    const float var  = sq * (1.f / 256.f) - mean * mean;
    const float r    = rsqrtf(var + EPS_);
    const float4 gg = *(const float4*)&g[ln * 4];
    const float4 bb = *(const float4*)&be[ln * 4];
    float4 o;
    o.x = (v0 - mean) * r * gg.x + bb.x;
    o.y = (v1 - mean) * r * gg.y + bb.y;
    o.z = (v2 - mean) * r * gg.z + bb.z;
    o.w = (v3 - mean) * r * gg.w + bb.w;
    *(float4*)&h[base] = o;
}

// ---------------------------------------------------------------------------
// Fused biased attention, online softmax (flash-style), f32.
// grid (B*H, N/8); block 256 = 8 q-rows x 32 lanes. No S matrix materialized.
// bias[b',h'][q][k]: f = b'*8+h'; i_emb = f>>5; b_src = f&31;
//   = spd<0 ? -1.0 : spd_emb[spd*8 + i_emb]
// ---------------------------------------------------------------------------
__global__ __launch_bounds__(256) void attn_kernel(const float* __restrict__ qkv,
                                                   const int* __restrict__ spd,
                                                   const float* __restrict__ semb,
                                                   float* __restrict__ out)
{
    __shared__ float Kt[64][34];  // pad 2 -> float2 reads conflict-free
    __shared__ float Vt[64][33];  // pad 1 -> scalar col reads conflict-free
    __shared__ float qs[8][33];
    __shared__ float pt[8][64];
    const int t  = threadIdx.x;
    const int bh = blockIdx.x;             // 0..255
    const int b  = bh >> 3, hd = bh & 7;
    const int ie = bh >> 5, bs = bh & 31;  // faithful "buggy" bias layout
    const int q0 = blockIdx.y * 8;
    const int qi = t >> 5, l = t & 31;
    const int qrow = q0 + qi;

    float qreg[32];
    {
        float qv = qkv[((size_t)b * N_ + qrow) * 768 + hd * 32 + l] * 0.17677669529663687f;
        qs[qi][l] = qv;   // same-wave write/read: in-order LDS, no barrier needed
    }
    #pragma unroll
    for (int d = 0; d < 32; d++) qreg[d] = qs[qi][d];

    float m = -INFINITY, ssum = 0.f, o = 0.f;
    const int* sp_row = spd + (size_t)bs * N_ * N_ + (size_t)qrow * N_;

    for (int k0 = 0; k0 < N_; k0 += 64) {
        __syncthreads();    // previous tile fully consumed
        #pragma unroll
        for (int rep = 0; rep < 4; rep++) {
            const int idx = rep * 256 + t;
            const int kk = idx >> 4, dh = (idx & 15) * 2;
            const size_t gb = ((size_t)b * N_ + k0 + kk) * 768 + hd * 32 + dh;
            const float2 kv = *(const float2*)&qkv[gb + 256];
            const float2 vv = *(const float2*)&qkv[gb + 512];
            Kt[kk][dh] = kv.x; Kt[kk][dh + 1] = kv.y;
            Vt[kk][dh] = vv.x; Vt[kk][dh + 1] = vv.y;
        }
        __syncthreads();

        float sc[2];
        #pragma unroll
        for (int hf = 0; hf < 2; hf++) {
            const int kk = l + hf * 32;
            float dot = 0.f;
            #pragma unroll
            for (int dh = 0; dh < 16; dh++) {
                const float2 kv = *(const float2*)&Kt[kk][dh * 2];
                dot = fmaf(qreg[dh * 2],     kv.x, dot);
                dot = fmaf(qreg[dh * 2 + 1], kv.y, dot);
            }
            const int spv = sp_row[k0 + kk];
            dot += (spv < 0) ? -1.0f : semb[spv * 8 + ie];
            sc[hf] = dot;
        }
        // online softmax over this 64-wide tile (32-lane group owns one q row)
        float tmax = fmaxf(sc[0], sc[1]);
        #pragma unroll
        for (int msk = 1; msk < 32; msk <<= 1) tmax = fmaxf(tmax, __shfl_xor(tmax, msk, 32));
        const float mnew  = fmaxf(m, tmax);
        const float alpha = __expf(m - mnew);
        const float p0 = __expf(sc[0] - mnew);
        const float p1 = __expf(sc[1] - mnew);
        float ps = p0 + p1;
        #pragma unroll
        for (int msk = 1; msk < 32; msk <<= 1) ps += __shfl_xor(ps, msk, 32);
        ssum = ssum * alpha + ps;
        m = mnew;
        o *= alpha;
        pt[qi][l]      = p0;   // same-wave producer/consumer: no barrier needed
        pt[qi][l + 32] = p1;
        #pragma unroll
        for (int kq = 0; kq < 16; kq++) {
            const float4 p4 = *(const float4*)&pt[qi][kq * 4];
            o = fmaf(p4.x, Vt[kq * 4 + 0][l], o);
            o = fmaf(p4.y, Vt[kq * 4 + 1][l], o);
            o = fmaf(p4.z, Vt[kq * 4 + 2][l], o);
            o = fmaf(p4.w, Vt[kq * 4 + 3][l], o);
        }
    }
    // [B,N,H,DH] layout == concat heads -> feeds Wo GEMM directly
    out[((size_t)b * N_ + qrow) * 256 + hd * 32 + l] = o / ssum;
}

// ---------------------------------------------------------------------------
extern "C" void kernel_launch(void* const* d_in, const int* in_sizes, int n_in,
                              void* d_out, int out_size, void* d_ws, size_t ws_size,
                              hipStream_t stream)
{
    const float* x    = (const float*)d_in[0];
    const int*   adj  = (const int*)  d_in[1];
    const int*   spd  = (const int*)  d_in[2];
    const float* Wf   = (const float*)d_in[3];
    const float* bf   = (const float*)d_in[4];
    const float* bn1g = (const float*)d_in[5];
    const float* bn1b = (const float*)d_in[6];
    const float* degE = (const float*)d_in[7];
    const float* semb = (const float*)d_in[8];
    const float* Wqkv = (const float*)d_in[9];
    const float* bqkv = (const float*)d_in[10];
    const float* Wo   = (const float*)d_in[11];
    const float* bo   = (const float*)d_in[12];
    const float* ln1g = (const float*)d_in[13];
    const float* ln1b = (const float*)d_in[14];
    const float* W1   = (const float*)d_in[15];
    const float* b1   = (const float*)d_in[16];
    const float* W2   = (const float*)d_in[17];
    const float* b2   = (const float*)d_in[18];
    const float* ln2g = (const float*)d_in[19];
    const float* ln2b = (const float*)d_in[20];
    const float* Win  = (const float*)d_in[21];
    const float* bin  = (const float*)d_in[22];
    const float* bn2g = (const float*)d_in[23];
    const float* bn2b = (const float*)d_in[24];

    float* h   = (float*)d_ws;
    float* t1  = h  + (size_t)ROWS * 256;   // [ROWS,768] scratch (qkv / pre-BN)
    float* t2  = t1 + (size_t)ROWS * 768;   // [ROWS,256]
    float* t3  = t2 + (size_t)ROWS * 256;   // [ROWS,256]
    int*   deg = (int*)(t3 + (size_t)ROWS * 256);
    float* bnp = (float*)(deg + ROWS);
    float* bnf = bnp + 64 * 512;

    const dim3 blk(256);
    const dim3 g256(ROWS / 64, 256 / 64);   // GEMM grids
    const dim3 g768(ROWS / 64, 768 / 64);

    // 1. lin_first: x @ Wf^T + bf -> BN -> LeakyReLU -> h
    gemm_nt<0><<<g256, blk, 0, stream>>>(x, Wf, bf, t1, ROWS, 256, 256);
    bn_partial <<<64,   blk, 0, stream>>>(t1, bnp);
    bn_finalize<<<1,    blk, 0, stream>>>(bnp, bn1g, bn1b, bnf);
    bn_apply_leaky<<<ROWS * 256 / 4 / 256, blk, 0, stream>>>(t1, bnf, h);

    // 2. degree embedding
    deg_kernel<<<dim3(B_, N_ / 256), blk, 0, stream>>>(adj, deg);
    deg_add   <<<ROWS * 256 / 4 / 256, blk, 0, stream>>>(deg, degE, h);

    // 3. transformer layers
    for (int l = 0; l < L_; l++) {
        gemm_nt<0><<<g768, blk, 0, stream>>>(h, Wqkv + (size_t)l * 768 * 256,
                                             bqkv + l * 768, t1, ROWS, 768, 256);
        attn_kernel<<<dim3(B_ * H_, N_ / 8), blk, 0, stream>>>(t1, spd, semb, t2);
        gemm_nt<0><<<g256, blk, 0, stream>>>(t2, Wo + (size_t)l * 256 * 256,
                                             bo + l * 256, t3, ROWS, 256, 256);
        add_ln<<<ROWS / 4, blk, 0, stream>>>(h, t3, ln1g + l * 256, ln1b + l * 256);
        gemm_nt<1><<<g256, blk, 0, stream>>>(h, W1 + (size_t)l * 256 * 256,
                                             b1 + l * 256, t2, ROWS, 256, 256);
        gemm_nt<0><<<g256, blk, 0, stream>>>(t2, W2 + (size_t)l * 256 * 256,
                                             b2 + l * 256, t3, ROWS, 256, 256);
        add_ln<<<ROWS / 4, blk, 0, stream>>>(h, t3, ln2g + l * 256, ln2b + l * 256);
    }

    // 4. lin_in: h @ Win^T + bin -> BN -> LeakyReLU -> out
    gemm_nt<0><<<g256, blk, 0, stream>>>(h, Win, bin, t1, ROWS, 256, 256);
    bn_partial <<<64, blk, 0, stream>>>(t1, bnp);
    bn_finalize<<<1,  blk, 0, stream>>>(bnp, bn2g, bn2b, bnf);
    bn_apply_leaky<<<ROWS * 256 / 4 / 256, blk, 0, stream>>>(t1, bnf, (float*)d_out);
}

// Round 2
// 1057.623 us; speedup vs baseline: 1.5745x; 1.5745x over previous
//
#include <hip/hip_runtime.h>
#include <hip/hip_bf16.h>
#include <math.h>

#define B_   32
#define N_   512
#define D_   256
#define H_   8
#define DH_  32
#define L_   2
#define ROWS (B_ * N_)          // 16384
#define EPS_ 1e-5f

typedef __attribute__((ext_vector_type(8))) short bf16x8;
typedef __attribute__((ext_vector_type(4))) float f32x4;

__device__ inline short f2bf(float f) {
    unsigned u = __builtin_bit_cast(unsigned, f);
    u += 0x7fffu + ((u >> 16) & 1u);          // round-to-nearest-even
    return (short)(u >> 16);
}

// ---------------------------------------------------------------------------
// Generic f32 GEMM:  C[m,n] = sum_k A[m,k] * W[n,k] + bias[n]   (NT layout)
// ---------------------------------------------------------------------------
template<int ACT>
__global__ __launch_bounds__(256) void gemm_nt(const float* __restrict__ A,
                                               const float* __restrict__ W,
                                               const float* __restrict__ bias,
                                               float* __restrict__ C,
                                               int M, int Nn, int K)
{
    __shared__ float As[32][68];
    __shared__ float Bs[32][68];
    const int t  = threadIdx.x;
    const int tx = t & 15, ty = t >> 4;
    const int m0 = blockIdx.x * 64;
    const int n0 = blockIdx.y * 64;
    const int krow = t >> 3;
    const int k4   = (t & 7) * 4;
    float acc[4][4] = {};

    for (int kb = 0; kb < K; kb += 32) {
        #pragma unroll
        for (int rr = 0; rr < 64; rr += 32) {
            float4 a = *(const float4*)&A[(size_t)(m0 + krow + rr) * K + kb + k4];
            As[k4 + 0][krow + rr] = a.x; As[k4 + 1][krow + rr] = a.y;
            As[k4 + 2][krow + rr] = a.z; As[k4 + 3][krow + rr] = a.w;
            float4 b = *(const float4*)&W[(size_t)(n0 + krow + rr) * K + kb + k4];
            Bs[k4 + 0][krow + rr] = b.x; Bs[k4 + 1][krow + rr] = b.y;
            Bs[k4 + 2][krow + rr] = b.z; Bs[k4 + 3][krow + rr] = b.w;
        }
        __syncthreads();
        #pragma unroll
        for (int k = 0; k < 32; k++) {
            float4 a4 = *(const float4*)&As[k][ty * 4];
            float4 b4 = *(const float4*)&Bs[k][tx * 4];
            float av[4] = {a4.x, a4.y, a4.z, a4.w};
            float bv[4] = {b4.x, b4.y, b4.z, b4.w};
            #pragma unroll
            for (int i = 0; i < 4; i++)
                #pragma unroll
                for (int j = 0; j < 4; j++)
                    acc[i][j] = fmaf(av[i], bv[j], acc[i][j]);
        }
        __syncthreads();
    }

    #pragma unroll
    for (int i = 0; i < 4; i++) {
        const int m = m0 + ty * 4 + i;
        float4 o;
        float* op = &o.x;
        #pragma unroll
        for (int j = 0; j < 4; j++) {
            float v = acc[i][j] + bias[n0 + tx * 4 + j];
            if (ACT == 1) v = fmaxf(v, 0.f);
            op[j] = v;
        }
        *(float4*)&C[(size_t)m * Nn + n0 + tx * 4] = o;
    }
}

// ---------------------------------------------------------------------------
// BatchNorm over dim0, two-stage deterministic.
// ---------------------------------------------------------------------------
__global__ __launch_bounds__(256) void bn_partial(const float* __restrict__ Y,
                                                  float* __restrict__ part)
{
    const int t = threadIdx.x, blk = blockIdx.x;
    float s = 0.f, sq = 0.f;
    const float* p = Y + (size_t)blk * 256 * 256 + t;
    for (int r = 0; r < 256; r++) {
        float v = p[(size_t)r * 256];
        s += v; sq += v * v;
    }
    part[blk * 512 + t]       = s;
    part[blk * 512 + 256 + t] = sq;
}

__global__ __launch_bounds__(256) void bn_finalize(const float* __restrict__ part,
                                                   const float* __restrict__ g,
                                                   const float* __restrict__ b,
                                                   float* __restrict__ sc)
{
    const int t = threadIdx.x;
    float s = 0.f, sq = 0.f;
    for (int i = 0; i < 64; i++) { s += part[i * 512 + t]; sq += part[i * 512 + 256 + t]; }
    const float mean = s * (1.f / (float)ROWS);
    const float var  = sq * (1.f / (float)ROWS) - mean * mean;
    const float k    = g[t] * rsqrtf(var + EPS_);
    sc[t]       = k;
    sc[256 + t] = b[t] - mean * k;
}

__global__ __launch_bounds__(256) void bn_apply_leaky(const float* __restrict__ Y,
                                                      const float* __restrict__ sc,
                                                      float* __restrict__ O)
{
    const int idx = blockIdx.x * 256 + threadIdx.x;
    const int c4  = (idx & 63) * 4;
    const float4 v  = *(const float4*)&Y[(size_t)idx * 4];
    const float4 k  = *(const float4*)&sc[c4];
    const float4 sh = *(const float4*)&sc[256 + c4];
    float4 o;
    o.x = fmaf(v.x, k.x, sh.x); o.x = o.x >= 0.f ? o.x : 0.01f * o.x;
    o.y = fmaf(v.y, k.y, sh.y); o.y = o.y >= 0.f ? o.y : 0.01f * o.y;
    o.z = fmaf(v.z, k.z, sh.z); o.z = o.z >= 0.f ? o.z : 0.01f * o.z;
    o.w = fmaf(v.w, k.w, sh.w); o.w = o.w >= 0.f ? o.w : 0.01f * o.w;
    *(float4*)&O[(size_t)idx * 4] = o;
}

// ---------------------------------------------------------------------------
// Degree
// ---------------------------------------------------------------------------
__global__ __launch_bounds__(256) void deg_kernel(const int* __restrict__ adj,
                                                  int* __restrict__ deg)
{
    const int b = blockIdx.x;
    const int j = blockIdx.y * 256 + threadIdx.x;
    const int* p = adj + (size_t)b * N_ * N_ + j;
    int c = 0;
    for (int i = 0; i < N_; i++) c += (p[(size_t)i * N_] != 0);
    deg[b * N_ + j] = c;
}

__global__ __launch_bounds__(256) void deg_add(const int* __restrict__ deg,
                                               const float* __restrict__ emb,
                                               float* __restrict__ h)
{
    const int idx = blockIdx.x * 256 + threadIdx.x;
    const int row = idx >> 6;
    const int c4  = (idx & 63) * 4;
    const int d   = deg[row];
    const float4 e = *(const float4*)&emb[(size_t)d * 256 + c4];
    float4 v = *(float4*)&h[(size_t)idx * 4];
    v.x += e.x; v.y += e.y; v.z += e.z; v.w += e.w;
    *(float4*)&h[(size_t)idx * 4] = v;
}

// ---------------------------------------------------------------------------
// Residual + LayerNorm
// ---------------------------------------------------------------------------
__global__ __launch_bounds__(256) void add_ln(float* __restrict__ h,
                                              const float* __restrict__ p,
                                              const float* __restrict__ g,
                                              const float* __restrict__ be)
{
    const int wv = threadIdx.x >> 6, ln = threadIdx.x & 63;
    const size_t row  = (size_t)blockIdx.x * 4 + wv;
    const size_t base = row * 256 + ln * 4;
    const float4 a = *(const float4*)&h[base];
    const float4 q = *(const float4*)&p[base];
    const float v0 = a.x + q.x, v1 = a.y + q.y, v2 = a.z + q.z, v3 = a.w + q.w;
    float s  = v0 + v1 + v2 + v3;
    float sq = v0 * v0 + v1 * v1 + v2 * v2 + v3 * v3;
    #pragma unroll
    for (int m = 1; m < 64; m <<= 1) {
        s  += __shfl_xor(s,  m, 64);
        sq += __shfl_xor(sq, m, 64);
    }
    const float mean = s * (1.f / 256.f);
    const float var  = sq * (1.f / 256.f) - mean * mean;
    const float r    = rsqrtf(var + EPS_);
    const float4 gg = *(const float4*)&g[ln * 4];
    const float4 bb = *(const float4*)&be[ln * 4];
    float4 o;
    o.x = (v0 - mean) * r * gg.x + bb.x;
    o.y = (v1 - mean) * r * gg.y + bb.y;
    o.z = (v2 - mean) * r * gg.z + bb.z;
    o.w = (v3 - mean) * r * gg.w + bb.w;
    *(float4*)&h[base] = o;
}

// ---------------------------------------------------------------------------
// MFMA bf16 flash attention.
// Block = 256 thr = 4 waves; one (b,h), 128 q-rows (wave: 32 q = 2 q-tiles).
// KV-tile = 128, staged f32->bf16 into LDS. Softmax per 16-lane group.
// mfma_f32_16x16x32_bf16; shared (lane,elem)->k map for A and B:
//   k = 8*(lane>>4)+i ; C/D: col=lane&15, row=4*(lane>>4)+reg (HW-verified).
// Bias enters as the MFMA C operand. spd locality via bs-grouped XCD swizzle.
// ---------------------------------------------------------------------------
#define KST 40    // K LDS row stride (bf16): 32 + 8 pad, 80 B (16B-aligned)
#define VST 136   // Vt LDS row stride: 128 + 8 pad, 272 B
#define PST 136   // P LDS row stride

__global__ __launch_bounds__(256) void attn_mfma(const float* __restrict__ qkv,
                                                 const int* __restrict__ spd,
                                                 const float* __restrict__ semb,
                                                 float* __restrict__ out)
{
    __shared__ short Kl[128 * KST];        // [k][dh]
    __shared__ short Vl[32 * VST];         // [dh][k]  (transposed)
    __shared__ short Pl[4][16 * PST];      // per-wave [q16][k128]

    const int t  = threadIdx.x, w = t >> 6, l = t & 63;
    const int lg = l >> 4, lr = l & 15;

    // bs-grouped XCD swizzle: xcd owns contiguous s-range -> 4 spd panels/XCD
    const int s   = ((blockIdx.x & 7) << 7) + (blockIdx.x >> 3);
    const int bs  = s >> 5, ie = (s >> 2) & 7, qb = s & 3;
    const int bh  = ie * 32 + bs, b = bh >> 3, hd = bh & 7;
    const int q0  = qb * 128 + w * 32;     // this wave's first q row

    // --- Q fragments (scaled), A-layout: row=lr, k=8*lg+i ---
    bf16x8 qf[2];
    #pragma unroll
    for (int qt = 0; qt < 2; qt++) {
        const float* qp = qkv + ((size_t)b * N_ + q0 + qt * 16 + lr) * 768 + hd * 32 + lg * 8;
        float4 a = *(const float4*)qp;
        float4 c = *(const float4*)(qp + 4);
        union { bf16x8 v; short sh[8]; } u;
        u.sh[0] = f2bf(a.x * 0.17677669529663687f);
        u.sh[1] = f2bf(a.y * 0.17677669529663687f);
        u.sh[2] = f2bf(a.z * 0.17677669529663687f);
        u.sh[3] = f2bf(a.w * 0.17677669529663687f);
        u.sh[4] = f2bf(c.x * 0.17677669529663687f);
        u.sh[5] = f2bf(c.y * 0.17677669529663687f);
        u.sh[6] = f2bf(c.z * 0.17677669529663687f);
        u.sh[7] = f2bf(c.w * 0.17677669529663687f);
        qf[qt] = u.v;
    }

    f32x4 oacc[2][2] = {};               // [qt][dh-col-tile], row r = 4*lg+r
    float mrun[2][4], srun[2][4];
    #pragma unroll
    for (int qt = 0; qt < 2; qt++)
        #pragma unroll
        for (int r = 0; r < 4; r++) { mrun[qt][r] = -INFINITY; srun[qt][r] = 0.f; }

    const int sr = t >> 1, shf = (t & 1) << 4;   // staging row / col-half

    for (int k0 = 0; k0 < N_; k0 += 128) {
        if (k0) __syncthreads();
        // ---- stage K tile [128][32] and V^T tile [32][128] (f32 -> bf16) ----
        {
            const float* kg = qkv + ((size_t)b * N_ + k0 + sr) * 768 + 256 + hd * 32 + shf;
            float4 f0 = *(const float4*)(kg);
            float4 f1 = *(const float4*)(kg + 4);
            float4 f2 = *(const float4*)(kg + 8);
            float4 f3 = *(const float4*)(kg + 12);
            union { bf16x8 v; short sh[8]; } p0, p1;
            p0.sh[0] = f2bf(f0.x); p0.sh[1] = f2bf(f0.y); p0.sh[2] = f2bf(f0.z); p0.sh[3] = f2bf(f0.w);
            p0.sh[4] = f2bf(f1.x); p0.sh[5] = f2bf(f1.y); p0.sh[6] = f2bf(f1.z); p0.sh[7] = f2bf(f1.w);
            p1.sh[0] = f2bf(f2.x); p1.sh[1] = f2bf(f2.y); p1.sh[2] = f2bf(f2.z); p1.sh[3] = f2bf(f2.w);
            p1.sh[4] = f2bf(f3.x); p1.sh[5] = f2bf(f3.y); p1.sh[6] = f2bf(f3.z); p1.sh[7] = f2bf(f3.w);
            *(bf16x8*)&Kl[sr * KST + shf]     = p0.v;
            *(bf16x8*)&Kl[sr * KST + shf + 8] = p1.v;

            const float* vg = kg + 256;
            float4 g0 = *(const float4*)(vg);
            float4 g1 = *(const float4*)(vg + 4);
            float4 g2 = *(const float4*)(vg + 8);
            float4 g3 = *(const float4*)(vg + 12);
            Vl[(shf + 0)  * VST + sr] = f2bf(g0.x);
            Vl[(shf + 1)  * VST + sr] = f2bf(g0.y);
            Vl[(shf + 2)  * VST + sr] = f2bf(g0.z);
            Vl[(shf + 3)  * VST + sr] = f2bf(g0.w);
            Vl[(shf + 4)  * VST + sr] = f2bf(g1.x);
            Vl[(shf + 5)  * VST + sr] = f2bf(g1.y);
            Vl[(shf + 6)  * VST + sr] = f2bf(g1.z);
            Vl[(shf + 7)  * VST + sr] = f2bf(g1.w);
            Vl[(shf + 8)  * VST + sr] = f2bf(g2.x);
            Vl[(shf + 9)  * VST + sr] = f2bf(g2.y);
            Vl[(shf + 10) * VST + sr] = f2bf(g2.z);
            Vl[(shf + 11) * VST + sr] = f2bf(g2.w);
            Vl[(shf + 12) * VST + sr] = f2bf(g3.x);
            Vl[(shf + 13) * VST + sr] = f2bf(g3.y);
            Vl[(shf + 14) * VST + sr] = f2bf(g3.z);
            Vl[(shf + 15) * VST + sr] = f2bf(g3.w);
        }
        __syncthreads();

        // ---- K and V fragments for this tile (shared across both q-tiles) ----
        bf16x8 kfr[8];
        #pragma unroll
        for (int ct = 0; ct < 8; ct++)
            kfr[ct] = *(const bf16x8*)&Kl[(ct * 16 + lr) * KST + lg * 8];
        bf16x8 vfr[4][2];
        #pragma unroll
        for (int kt = 0; kt < 4; kt++)
            #pragma unroll
            for (int c2 = 0; c2 < 2; c2++)
                vfr[kt][c2] = *(const bf16x8*)&Vl[(c2 * 16 + lr) * VST + kt * 32 + lg * 8];

        #pragma unroll
        for (int qt = 0; qt < 2; qt++) {
            const int qg = q0 + qt * 16 + 4 * lg;      // + r
            // S = Q K^T + bias (bias as C operand)
            f32x4 sA[8];
            #pragma unroll
            for (int ct = 0; ct < 8; ct++) {
                f32x4 c;
                #pragma unroll
                for (int r = 0; r < 4; r++) {
                    const int sv = spd[((size_t)bs * N_ + qg + r) * N_ + k0 + ct * 16 + lr];
                    c[r] = (sv < 0) ? -1.0f : semb[sv * 8 + ie];
                }
                sA[ct] = __builtin_amdgcn_mfma_f32_16x16x32_bf16(qf[qt], kfr[ct], c, 0, 0, 0);
            }
            // online softmax per row r (16-lane groups share a row)
            float tmax[4];
            #pragma unroll
            for (int r = 0; r < 4; r++) {
                float m = sA[0][r];
                #pragma unroll
                for (int ct = 1; ct < 8; ct++) m = fmaxf(m, sA[ct][r]);
                #pragma unroll
                for (int msk = 1; msk < 16; msk <<= 1) m = fmaxf(m, __shfl_xor(m, msk, 64));
                tmax[r] = m;
            }
            float alpha[4], psum[4];
            #pragma unroll
            for (int r = 0; r < 4; r++) {
                const float mnew = fmaxf(mrun[qt][r], tmax[r]);
                alpha[r] = __expf(mrun[qt][r] - mnew);
                mrun[qt][r] = mnew;
                psum[r] = 0.f;
            }
            #pragma unroll
            for (int ct = 0; ct < 8; ct++) {
                #pragma unroll
                for (int r = 0; r < 4; r++) {
                    const float p = __expf(sA[ct][r] - mrun[qt][r]);
                    psum[r] += p;
                    Pl[w][(4 * lg + r) * PST + ct * 16 + lr] = f2bf(p);
                }
            }
            #pragma unroll
            for (int r = 0; r < 4; r++) {
                float ps = psum[r];
                #pragma unroll
                for (int msk = 1; msk < 16; msk <<= 1) ps += __shfl_xor(ps, msk, 64);
                srun[qt][r] = srun[qt][r] * alpha[r] + ps;
                oacc[qt][0][r] *= alpha[r];
                oacc[qt][1][r] *= alpha[r];
            }
            // O += P V
            #pragma unroll
            for (int kt = 0; kt < 4; kt++) {
                const bf16x8 pa = *(const bf16x8*)&Pl[w][lr * PST + kt * 32 + lg * 8];
                #pragma unroll
                for (int c2 = 0; c2 < 2; c2++)
                    oacc[qt][c2] = __builtin_amdgcn_mfma_f32_16x16x32_bf16(pa, vfr[kt][c2],
                                                                           oacc[qt][c2], 0, 0, 0);
            }
        }
    }

    // ---- write O / srun -> [B,N,H,DH] (== concat heads) ----
    #pragma unroll
    for (int qt = 0; qt < 2; qt++)
        #pragma unroll
        for (int c2 = 0; c2 < 2; c2++)
            #pragma unroll
            for (int r = 0; r < 4; r++) {
                const int qrow = q0 + qt * 16 + 4 * lg + r;
                out[((size_t)b * N_ + qrow) * 256 + hd * 32 + c2 * 16 + lr] =
                    oacc[qt][c2][r] / srun[qt][r];
            }
}

// ---------------------------------------------------------------------------
extern "C" void kernel_launch(void* const* d_in, const int* in_sizes, int n_in,
                              void* d_out, int out_size, void* d_ws, size_t ws_size,
                              hipStream_t stream)
{
    const float* x    = (const float*)d_in[0];
    const int*   adj  = (const int*)  d_in[1];
    const int*   spd  = (const int*)  d_in[2];
    const float* Wf   = (const float*)d_in[3];
    const float* bf   = (const float*)d_in[4];
    const float* bn1g = (const float*)d_in[5];
    const float* bn1b = (const float*)d_in[6];
    const float* degE = (const float*)d_in[7];
    const float* semb = (const float*)d_in[8];
    const float* Wqkv = (const float*)d_in[9];
    const float* bqkv = (const float*)d_in[10];
    const float* Wo   = (const float*)d_in[11];
    const float* bo   = (const float*)d_in[12];
    const float* ln1g = (const float*)d_in[13];
    const float* ln1b = (const float*)d_in[14];
    const float* W1   = (const float*)d_in[15];
    const float* b1   = (const float*)d_in[16];
    const float* W2   = (const float*)d_in[17];
    const float* b2   = (const float*)d_in[18];
    const float* ln2g = (const float*)d_in[19];
    const float* ln2b = (const float*)d_in[20];
    const float* Win  = (const float*)d_in[21];
    const float* bin  = (const float*)d_in[22];
    const float* bn2g = (const float*)d_in[23];
    const float* bn2b = (const float*)d_in[24];

    float* h   = (float*)d_ws;
    float* t1  = h  + (size_t)ROWS * 256;   // [ROWS,768] qkv / pre-BN scratch
    float* t2  = t1 + (size_t)ROWS * 768;
    float* t3  = t2 + (size_t)ROWS * 256;
    int*   deg = (int*)(t3 + (size_t)ROWS * 256);
    float* bnp = (float*)(deg + ROWS);
    float* bnf = bnp + 64 * 512;

    const dim3 blk(256);
    const dim3 g256(ROWS / 64, 256 / 64);
    const dim3 g768(ROWS / 64, 768 / 64);

    gemm_nt<0><<<g256, blk, 0, stream>>>(x, Wf, bf, t1, ROWS, 256, 256);
    bn_partial <<<64,   blk, 0, stream>>>(t1, bnp);
    bn_finalize<<<1,    blk, 0, stream>>>(bnp, bn1g, bn1b, bnf);
    bn_apply_leaky<<<ROWS * 256 / 4 / 256, blk, 0, stream>>>(t1, bnf, h);

    deg_kernel<<<dim3(B_, N_ / 256), blk, 0, stream>>>(adj, deg);
    deg_add   <<<ROWS * 256 / 4 / 256, blk, 0, stream>>>(deg, degE, h);

    for (int l = 0; l < L_; l++) {
        gemm_nt<0><<<g768, blk, 0, stream>>>(h, Wqkv + (size_t)l * 768 * 256,
                                             bqkv + l * 768, t1, ROWS, 768, 256);
        attn_mfma<<<1024, blk, 0, stream>>>(t1, spd, semb, t2);
        gemm_nt<0><<<g256, blk, 0, stream>>>(t2, Wo + (size_t)l * 256 * 256,
                                             bo + l * 256, t3, ROWS, 256, 256);
        add_ln<<<ROWS / 4, blk, 0, stream>>>(h, t3, ln1g + l * 256, ln1b + l * 256);
        gemm_nt<1><<<g256, blk, 0, stream>>>(h, W1 + (size_t)l * 256 * 256,
                                             b1 + l * 256, t2, ROWS, 256, 256);
        gemm_nt<0><<<g256, blk, 0, stream>>>(t2, W2 + (size_t)l * 256 * 256,
                                             b2 + l * 256, t3, ROWS, 256, 256);
        add_ln<<<ROWS / 4, blk, 0, stream>>>(h, t3, ln2g + l * 256, ln2b + l * 256);
    }

    gemm_nt<0><<<g256, blk, 0, stream>>>(h, Win, bin, t1, ROWS, 256, 256);
    bn_partial <<<64, blk, 0, stream>>>(t1, bnp);
    bn_finalize<<<1,  blk, 0, stream>>>(bnp, bn2g, bn2b, bnf);
    bn_apply_leaky<<<ROWS * 256 / 4 / 256, blk, 0, stream>>>(t1, bnf, (float*)d_out);
}

// Round 4
// 713.004 us; speedup vs baseline: 2.3355x; 1.4833x over previous
//
#include <hip/hip_runtime.h>
#include <hip/hip_bf16.h>
#include <math.h>

#define B_   32
#define N_   512
#define D_   256
#define H_   8
#define DH_  32
#define L_   2
#define ROWS (B_ * N_)          // 16384
#define EPS_ 1e-5f

typedef __attribute__((ext_vector_type(8))) short bf16x8;
typedef __attribute__((ext_vector_type(4))) float f32x4;

__device__ __forceinline__ short f2bf(float f) {
    unsigned u = __builtin_bit_cast(unsigned, f);
    u += 0x7fffu + ((u >> 16) & 1u);          // round-to-nearest-even
    return (short)(u >> 16);
}

__device__ __forceinline__ void gl_lds16(const short* g, short* l) {
    __builtin_amdgcn_global_load_lds(
        (const __attribute__((address_space(1))) unsigned int*)g,
        (__attribute__((address_space(3))) unsigned int*)l, 16, 0, 0);
}

// ---------------------------------------------------------------------------
// One-shot f32 -> bf16 conversion of x and all GEMM weights.
// ---------------------------------------------------------------------------
__global__ __launch_bounds__(256) void cvt_all(const float* __restrict__ x,
                                               const float* __restrict__ wf,
                                               const float* __restrict__ wq,
                                               const float* __restrict__ wo,
                                               const float* __restrict__ w1,
                                               const float* __restrict__ w2,
                                               const float* __restrict__ wi,
                                               short* __restrict__ xb,
                                               short* __restrict__ wb)
{
    const int u = blockIdx.x * 256 + threadIdx.x;
    if (u >= 638976) return;
    const float* s; short* d; int off;
    if      (u < 524288) { s = x;  d = xb;          off = u; }
    else if (u < 532480) { s = wf; d = wb;          off = u - 524288; }
    else if (u < 581632) { s = wq; d = wb + 65536;  off = u - 532480; }
    else if (u < 598016) { s = wo; d = wb + 458752; off = u - 581632; }
    else if (u < 614400) { s = w1; d = wb + 589824; off = u - 598016; }
    else if (u < 630784) { s = w2; d = wb + 720896; off = u - 614400; }
    else                 { s = wi; d = wb + 851968; off = u - 630784; }
    const float4 a = ((const float4*)s)[off * 2];
    const float4 b = ((const float4*)s)[off * 2 + 1];
    bf16x8 o;
    o[0] = f2bf(a.x); o[1] = f2bf(a.y); o[2] = f2bf(a.z); o[3] = f2bf(a.w);
    o[4] = f2bf(b.x); o[5] = f2bf(b.y); o[6] = f2bf(b.z); o[7] = f2bf(b.w);
    *(bf16x8*)(d + (size_t)off * 8) = o;
}

// ---------------------------------------------------------------------------
// bf16 MFMA GEMM (NT): C[m,n] = sum_k A[m,k]*W[n,k] + bias[n]
// 128x128 tile, BK=64, 256 thr (2x2 waves, 64x64 each), 16x16x32 MFMA.
// LDS [128][64] staged via global_load_lds(16B), source pre-swizzled
// LDS(row, slot) = G(row, slot ^ (row&7)); read applies same XOR.
// Fragment k-slot = lg + ks*4  (k = ks*32 + lg*8 + i).
// FLAGS: 1=f32 out, 2=bf16 out, 4=relu, 8=qscale(first 256 cols).
// ---------------------------------------------------------------------------
template<int FLAGS>
__global__ __launch_bounds__(256) void gemm_bf16(const short* __restrict__ A,
                                                 const short* __restrict__ Bw,
                                                 const float* __restrict__ bias,
                                                 float* __restrict__ Cf,
                                                 short* __restrict__ Cb,
                                                 int M, int Nn, int K)
{
    __shared__ short Al[128 * 64];
    __shared__ short Bl[128 * 64];
    const int t = threadIdx.x, w = t >> 6, l = t & 63;
    const int lg = l >> 4, lr = l & 15;
    const int wm = w >> 1, wn = w & 1;
    const int m0 = blockIdx.x * 128, n0 = blockIdx.y * 128;
    const int srow = w * 32 + (l >> 3), sslot = l & 7;

    f32x4 acc[4][4] = {};

    for (int kb = 0; kb < K; kb += 64) {
        if (kb) __syncthreads();
        #pragma unroll
        for (int j = 0; j < 4; j++) {
            const int ra = srow + j * 8;
            const int sw = (sslot ^ (ra & 7)) << 3;
            gl_lds16(A  + (size_t)(m0 + ra) * K + kb + sw, &Al[(w * 32 + j * 8) * 64]);
            gl_lds16(Bw + (size_t)(n0 + ra) * K + kb + sw, &Bl[(w * 32 + j * 8) * 64]);
        }
        __syncthreads();   // compiler drains vmcnt before barrier
        #pragma unroll
        for (int ks = 0; ks < 2; ks++) {
            bf16x8 af[4], bfr[4];
            #pragma unroll
            for (int i = 0; i < 4; i++) {
                const int ar = wm * 64 + i * 16 + lr;
                af[i]  = *(const bf16x8*)&Al[ar * 64 + (((lg + ks * 4) ^ (ar & 7)) << 3)];
                const int br = wn * 64 + i * 16 + lr;
                bfr[i] = *(const bf16x8*)&Bl[br * 64 + (((lg + ks * 4) ^ (br & 7)) << 3)];
            }
            #pragma unroll
            for (int mi = 0; mi < 4; mi++)
                #pragma unroll
                for (int ni = 0; ni < 4; ni++)
                    acc[mi][ni] = __builtin_amdgcn_mfma_f32_16x16x32_bf16(af[mi], bfr[ni],
                                                                          acc[mi][ni], 0, 0, 0);
        }
    }

    #pragma unroll
    for (int ni = 0; ni < 4; ni++) {
        const int n = n0 + wn * 64 + ni * 16 + lr;
        const float bv = bias[n];
        const float qs = ((FLAGS & 8) && n < 256) ? 0.17677669529663687f : 1.0f;
        #pragma unroll
        for (int mi = 0; mi < 4; mi++) {
            #pragma unroll
            for (int r = 0; r < 4; r++) {
                const int m = m0 + wm * 64 + mi * 16 + 4 * lg + r;
                float v = (acc[mi][ni][r] + bv) * qs;
                if (FLAGS & 4) v = fmaxf(v, 0.f);
                if (FLAGS & 1) Cf[(size_t)m * Nn + n] = v;
                if (FLAGS & 2) Cb[(size_t)m * Nn + n] = f2bf(v);
            }
        }
    }
}

// ---------------------------------------------------------------------------
// BatchNorm over dim0, two-stage deterministic.
// ---------------------------------------------------------------------------
__global__ __launch_bounds__(256) void bn_partial(const float* __restrict__ Y,
                                                  float* __restrict__ part)
{
    const int t = threadIdx.x, blk = blockIdx.x;
    float s = 0.f, sq = 0.f;
    const float* p = Y + (size_t)blk * 256 * 256 + t;
    for (int r = 0; r < 256; r++) {
        float v = p[(size_t)r * 256];
        s += v; sq += v * v;
    }
    part[blk * 512 + t]       = s;
    part[blk * 512 + 256 + t] = sq;
}

__global__ __launch_bounds__(256) void bn_finalize(const float* __restrict__ part,
                                                   const float* __restrict__ g,
                                                   const float* __restrict__ b,
                                                   float* __restrict__ sc)
{
    const int t = threadIdx.x;
    float s = 0.f, sq = 0.f;
    for (int i = 0; i < 64; i++) { s += part[i * 512 + t]; sq += part[i * 512 + 256 + t]; }
    const float mean = s * (1.f / (float)ROWS);
    const float var  = sq * (1.f / (float)ROWS) - mean * mean;
    const float k    = g[t] * rsqrtf(var + EPS_);
    sc[t]       = k;
    sc[256 + t] = b[t] - mean * k;
}

__global__ __launch_bounds__(256) void bn_apply_leaky(const float* __restrict__ Y,
                                                      const float* __restrict__ sc,
                                                      float* __restrict__ O)
{
    const int idx = blockIdx.x * 256 + threadIdx.x;
    const int c4  = (idx & 63) * 4;
    const float4 v  = *(const float4*)&Y[(size_t)idx * 4];
    const float4 k  = *(const float4*)&sc[c4];
    const float4 sh = *(const float4*)&sc[256 + c4];
    float4 o;
    o.x = fmaf(v.x, k.x, sh.x); o.x = o.x >= 0.f ? o.x : 0.01f * o.x;
    o.y = fmaf(v.y, k.y, sh.y); o.y = o.y >= 0.f ? o.y : 0.01f * o.y;
    o.z = fmaf(v.z, k.z, sh.z); o.z = o.z >= 0.f ? o.z : 0.01f * o.z;
    o.w = fmaf(v.w, k.w, sh.w); o.w = o.w >= 0.f ? o.w : 0.01f * o.w;
    *(float4*)&O[(size_t)idx * 4] = o;
}

// ---------------------------------------------------------------------------
// Degree
// ---------------------------------------------------------------------------
__global__ __launch_bounds__(256) void deg_kernel(const int* __restrict__ adj,
                                                  int* __restrict__ deg)
{
    const int b = blockIdx.x;
    const int j = blockIdx.y * 256 + threadIdx.x;
    const int* p = adj + (size_t)b * N_ * N_ + j;
    int c = 0;
    for (int i = 0; i < N_; i++) c += (p[(size_t)i * N_] != 0);
    deg[b * N_ + j] = c;
}

// h += deg_emb[deg];  also emits bf16 copy of h
__global__ __launch_bounds__(256) void deg_add2(const int* __restrict__ deg,
                                                const float* __restrict__ emb,
                                                float* __restrict__ h,
                                                short* __restrict__ hb)
{
    const int idx = blockIdx.x * 256 + threadIdx.x;
    const int row = idx >> 6;
    const int c4  = (idx & 63) * 4;
    const int d   = deg[row];
    const float4 e = *(const float4*)&emb[(size_t)d * 256 + c4];
    float4 v = *(float4*)&h[(size_t)idx * 4];
    v.x += e.x; v.y += e.y; v.z += e.z; v.w += e.w;
    *(float4*)&h[(size_t)idx * 4] = v;
    short4 s; s.x = f2bf(v.x); s.y = f2bf(v.y); s.z = f2bf(v.z); s.w = f2bf(v.w);
    *(short4*)&hb[(size_t)idx * 4] = s;
}

// ---------------------------------------------------------------------------
// Residual + LayerNorm, writes h (f32) and hb (bf16)
// ---------------------------------------------------------------------------
__global__ __launch_bounds__(256) void add_ln2(float* __restrict__ h,
                                               short* __restrict__ hb,
                                               const float* __restrict__ p,
                                               const float* __restrict__ g,
                                               const float* __restrict__ be)
{
    const int wv = threadIdx.x >> 6, ln = threadIdx.x & 63;
    const size_t row  = (size_t)blockIdx.x * 4 + wv;
    const size_t base = row * 256 + ln * 4;
    const float4 a = *(const float4*)&h[base];
    const float4 q = *(const float4*)&p[base];
    const float v0 = a.x + q.x, v1 = a.y + q.y, v2 = a.z + q.z, v3 = a.w + q.w;
    float s  = v0 + v1 + v2 + v3;
    float sq = v0 * v0 + v1 * v1 + v2 * v2 + v3 * v3;
    #pragma unroll
    for (int m = 1; m < 64; m <<= 1) {
        s  += __shfl_xor(s,  m, 64);
        sq += __shfl_xor(sq, m, 64);
    }
    const float mean = s * (1.f / 256.f);
    const float var  = sq * (1.f / 256.f) - mean * mean;
    const float r    = rsqrtf(var + EPS_);
    const float4 gg = *(const float4*)&g[ln * 4];
    const float4 bb = *(const float4*)&be[ln * 4];
    float4 o;
    o.x = (v0 - mean) * r * gg.x + bb.x;
    o.y = (v1 - mean) * r * gg.y + bb.y;
    o.z = (v2 - mean) * r * gg.z + bb.z;
    o.w = (v3 - mean) * r * gg.w + bb.w;
    *(float4*)&h[base] = o;
    short4 sb; sb.x = f2bf(o.x); sb.y = f2bf(o.y); sb.z = f2bf(o.z); sb.w = f2bf(o.w);
    *(short4*)&hb[base] = sb;
}

// ---------------------------------------------------------------------------
// MFMA bf16 flash attention (bf16 qkv in, Q pre-scaled; bf16 out).
// ---------------------------------------------------------------------------
#define KST 40    // K LDS row stride (bf16)
#define VST 136   // Vt LDS row stride
#define PST 136   // P LDS row stride

__global__ __launch_bounds__(256) void attn_mfma(const short* __restrict__ qkv,
                                                 const int* __restrict__ spd,
                                                 const float* __restrict__ semb,
                                                 short* __restrict__ out)
{
    __shared__ short Kl[128 * KST];
    __shared__ short Vl[32 * VST];
    __shared__ short Pl[4][16 * PST];

    const int t  = threadIdx.x, w = t >> 6, l = t & 63;
    const int lg = l >> 4, lr = l & 15;

    const int s   = ((blockIdx.x & 7) << 7) + (blockIdx.x >> 3);
    const int bs  = s >> 5, ie = (s >> 2) & 7, qb = s & 3;
    const int bh  = ie * 32 + bs, b = bh >> 3, hd = bh & 7;
    const int q0  = qb * 128 + w * 32;

    bf16x8 qf[2];
    #pragma unroll
    for (int qt = 0; qt < 2; qt++)
        qf[qt] = *(const bf16x8*)&qkv[((size_t)b * N_ + q0 + qt * 16 + lr) * 768 + hd * 32 + lg * 8];

    f32x4 oacc[2][2] = {};
    float mrun[2][4], srun[2][4];
    #pragma unroll
    for (int qt = 0; qt < 2; qt++)
        #pragma unroll
        for (int r = 0; r < 4; r++) { mrun[qt][r] = -INFINITY; srun[qt][r] = 0.f; }

    const int sr = t >> 1, shf = (t & 1) << 4;

    for (int k0 = 0; k0 < N_; k0 += 128) {
        if (k0) __syncthreads();
        {
            const short* kg = qkv + ((size_t)b * N_ + k0 + sr) * 768 + 256 + hd * 32 + shf;
            *(bf16x8*)&Kl[sr * KST + shf]     = *(const bf16x8*)kg;
            *(bf16x8*)&Kl[sr * KST + shf + 8] = *(const bf16x8*)(kg + 8);
            const bf16x8 v0 = *(const bf16x8*)(kg + 256);
            const bf16x8 v1 = *(const bf16x8*)(kg + 264);
            #pragma unroll
            for (int i = 0; i < 8; i++) {
                Vl[(shf + i)     * VST + sr] = v0[i];
                Vl[(shf + 8 + i) * VST + sr] = v1[i];
            }
        }
        __syncthreads();

        bf16x8 kfr[8];
        #pragma unroll
        for (int ct = 0; ct < 8; ct++)
            kfr[ct] = *(const bf16x8*)&Kl[(ct * 16 + lr) * KST + lg * 8];
        bf16x8 vfr[4][2];
        #pragma unroll
        for (int kt = 0; kt < 4; kt++)
            #pragma unroll
            for (int c2 = 0; c2 < 2; c2++)
                vfr[kt][c2] = *(const bf16x8*)&Vl[(c2 * 16 + lr) * VST + kt * 32 + lg * 8];

        #pragma unroll
        for (int qt = 0; qt < 2; qt++) {
            const int qg = q0 + qt * 16 + 4 * lg;
            f32x4 sA[8];
            #pragma unroll
            for (int ct = 0; ct < 8; ct++) {
                f32x4 c;
                #pragma unroll
                for (int r = 0; r < 4; r++) {
                    const int sv = spd[((size_t)bs * N_ + qg + r) * N_ + k0 + ct * 16 + lr];
                    c[r] = (sv < 0) ? -1.0f : semb[sv * 8 + ie];
                }
                sA[ct] = __builtin_amdgcn_mfma_f32_16x16x32_bf16(qf[qt], kfr[ct], c, 0, 0, 0);
            }
            float tmax[4];
            #pragma unroll
            for (int r = 0; r < 4; r++) {
                float m = sA[0][r];
                #pragma unroll
                for (int ct = 1; ct < 8; ct++) m = fmaxf(m, sA[ct][r]);
                #pragma unroll
                for (int msk = 1; msk < 16; msk <<= 1) m = fmaxf(m, __shfl_xor(m, msk, 64));
                tmax[r] = m;
            }
            float alpha[4], psum[4];
            #pragma unroll
            for (int r = 0; r < 4; r++) {
                const float mnew = fmaxf(mrun[qt][r], tmax[r]);
                alpha[r] = __expf(mrun[qt][r] - mnew);
                mrun[qt][r] = mnew;
                psum[r] = 0.f;
            }
            #pragma unroll
            for (int ct = 0; ct < 8; ct++) {
                #pragma unroll
                for (int r = 0; r < 4; r++) {
                    const float p = __expf(sA[ct][r] - mrun[qt][r]);
                    psum[r] += p;
                    Pl[w][(4 * lg + r) * PST + ct * 16 + lr] = f2bf(p);
                }
            }
            #pragma unroll
            for (int r = 0; r < 4; r++) {
                float ps = psum[r];
                #pragma unroll
                for (int msk = 1; msk < 16; msk <<= 1) ps += __shfl_xor(ps, msk, 64);
                srun[qt][r] = srun[qt][r] * alpha[r] + ps;
                oacc[qt][0][r] *= alpha[r];
                oacc[qt][1][r] *= alpha[r];
            }
            #pragma unroll
            for (int kt = 0; kt < 4; kt++) {
                const bf16x8 pa = *(const bf16x8*)&Pl[w][lr * PST + kt * 32 + lg * 8];
                #pragma unroll
                for (int c2 = 0; c2 < 2; c2++)
                    oacc[qt][c2] = __builtin_amdgcn_mfma_f32_16x16x32_bf16(pa, vfr[kt][c2],
                                                                           oacc[qt][c2], 0, 0, 0);
            }
        }
    }

    #pragma unroll
    for (int qt = 0; qt < 2; qt++)
        #pragma unroll
        for (int c2 = 0; c2 < 2; c2++)
            #pragma unroll
            for (int r = 0; r < 4; r++) {
                const int qrow = q0 + qt * 16 + 4 * lg + r;
                out[((size_t)b * N_ + qrow) * 256 + hd * 32 + c2 * 16 + lr] =
                    f2bf(oacc[qt][c2][r] / srun[qt][r]);
            }
}

// ---------------------------------------------------------------------------
extern "C" void kernel_launch(void* const* d_in, const int* in_sizes, int n_in,
                              void* d_out, int out_size, void* d_ws, size_t ws_size,
                              hipStream_t stream)
{
    const float* x    = (const float*)d_in[0];
    const int*   adj  = (const int*)  d_in[1];
    const int*   spd  = (const int*)  d_in[2];
    const float* Wf   = (const float*)d_in[3];
    const float* bf   = (const float*)d_in[4];
    const float* bn1g = (const float*)d_in[5];
    const float* bn1b = (const float*)d_in[6];
    const float* degE = (const float*)d_in[7];
    const float* semb = (const float*)d_in[8];
    const float* Wqkv = (const float*)d_in[9];
    const float* bqkv = (const float*)d_in[10];
    const float* Wo   = (const float*)d_in[11];
    const float* bo   = (const float*)d_in[12];
    const float* ln1g = (const float*)d_in[13];
    const float* ln1b = (const float*)d_in[14];
    const float* W1   = (const float*)d_in[15];
    const float* b1   = (const float*)d_in[16];
    const float* W2   = (const float*)d_in[17];
    const float* b2   = (const float*)d_in[18];
    const float* ln2g = (const float*)d_in[19];
    const float* ln2b = (const float*)d_in[20];
    const float* Win  = (const float*)d_in[21];
    const float* bin  = (const float*)d_in[22];
    const float* bn2g = (const float*)d_in[23];
    const float* bn2b = (const float*)d_in[24];

    char* p = (char*)d_ws;
    float* h    = (float*)p;  p += (size_t)ROWS * 256 * 4;
    float* t3   = (float*)p;  p += (size_t)ROWS * 256 * 4;
    char*  shr  = p;          p += (size_t)ROWS * 768 * 2;   // t1(f32) / qkvb(bf16)
    float* t1   = (float*)shr;
    short* qkvb = (short*)shr;
    short* hb   = (short*)p;  p += (size_t)ROWS * 256 * 2;
    short* t2b  = (short*)p;  p += (size_t)ROWS * 256 * 2;
    short* xb   = (short*)p;  p += (size_t)ROWS * 256 * 2;
    short* wb   = (short*)p;  p += (size_t)917504 * 2;
    int*   deg  = (int*)p;    p += (size_t)ROWS * 4;
    float* bnp  = (float*)p;  p += 64 * 512 * 4;
    float* bnf  = (float*)p;

    const short* wfb = wb;
    const short* wqb = wb + 65536;
    const short* wob = wb + 458752;
    const short* w1b = wb + 589824;
    const short* w2b = wb + 720896;
    const short* wib = wb + 851968;

    const dim3 blk(256);
    const dim3 g256(128, 2);    // M/128 x 256/128
    const dim3 g768(128, 6);    // M/128 x 768/128

    cvt_all<<<2496, blk, 0, stream>>>(x, Wf, Wqkv, Wo, W1, W2, Win, xb, wb);

    // 1. lin_first
    gemm_bf16<1><<<g256, blk, 0, stream>>>(xb, wfb, bf, t1, nullptr, ROWS, 256, 256);
    bn_partial <<<64, blk, 0, stream>>>(t1, bnp);
    bn_finalize<<<1,  blk, 0, stream>>>(bnp, bn1g, bn1b, bnf);
    bn_apply_leaky<<<ROWS * 256 / 4 / 256, blk, 0, stream>>>(t1, bnf, h);

    // 2. degree embedding
    deg_kernel<<<dim3(B_, N_ / 256), blk, 0, stream>>>(adj, deg);
    deg_add2  <<<ROWS * 256 / 4 / 256, blk, 0, stream>>>(deg, degE, h, hb);

    // 3. transformer layers
    for (int l = 0; l < L_; l++) {
        gemm_bf16<2 | 8><<<g768, blk, 0, stream>>>(hb, wqb + (size_t)l * 768 * 256,
                                                   bqkv + l * 768, nullptr, qkvb, ROWS, 768, 256);
        attn_mfma<<<1024, blk, 0, stream>>>(qkvb, spd, semb, t2b);
        gemm_bf16<1><<<g256, blk, 0, stream>>>(t2b, wob + (size_t)l * 256 * 256,
                                               bo + l * 256, t3, nullptr, ROWS, 256, 256);
        add_ln2<<<ROWS / 4, blk, 0, stream>>>(h, hb, t3, ln1g + l * 256, ln1b + l * 256);
        gemm_bf16<2 | 4><<<g256, blk, 0, stream>>>(hb, w1b + (size_t)l * 256 * 256,
                                                   b1 + l * 256, nullptr, t2b, ROWS, 256, 256);
        gemm_bf16<1><<<g256, blk, 0, stream>>>(t2b, w2b + (size_t)l * 256 * 256,
                                               b2 + l * 256, t3, nullptr, ROWS, 256, 256);
        add_ln2<<<ROWS / 4, blk, 0, stream>>>(h, hb, t3, ln2g + l * 256, ln2b + l * 256);
    }

    // 4. lin_in
    gemm_bf16<1><<<g256, blk, 0, stream>>>(hb, wib, bin, t1, nullptr, ROWS, 256, 256);
    bn_partial <<<64, blk, 0, stream>>>(t1, bnp);
    bn_finalize<<<1,  blk, 0, stream>>>(bnp, bn2g, bn2b, bnf);
    bn_apply_leaky<<<ROWS * 256 / 4 / 256, blk, 0, stream>>>(t1, bnf, (float*)d_out);
}

// Round 5
// 510.935 us; speedup vs baseline: 3.2592x; 1.3955x over previous
//
#include <hip/hip_runtime.h>
#include <hip/hip_bf16.h>
#include <math.h>

#define B_   32
#define N_   512
#define D_   256
#define H_   8
#define DH_  32
#define L_   2
#define ROWS (B_ * N_)          // 16384
#define EPS_ 1e-5f

typedef __attribute__((ext_vector_type(8))) short bf16x8;
typedef __attribute__((ext_vector_type(4))) float f32x4;

__device__ __forceinline__ short f2bf(float f) {
    unsigned u = __builtin_bit_cast(unsigned, f);
    u += 0x7fffu + ((u >> 16) & 1u);          // round-to-nearest-even
    return (short)(u >> 16);
}

__device__ __forceinline__ void gl_lds16(const short* g, short* l) {
    __builtin_amdgcn_global_load_lds(
        (const __attribute__((address_space(1))) unsigned int*)g,
        (__attribute__((address_space(3))) unsigned int*)l, 16, 0, 0);
}

// ---------------------------------------------------------------------------
// One-shot f32 -> bf16 conversion of x and all GEMM weights.
// ---------------------------------------------------------------------------
__global__ __launch_bounds__(256) void cvt_all(const float* __restrict__ x,
                                               const float* __restrict__ wf,
                                               const float* __restrict__ wq,
                                               const float* __restrict__ wo,
                                               const float* __restrict__ w1,
                                               const float* __restrict__ w2,
                                               const float* __restrict__ wi,
                                               short* __restrict__ xb,
                                               short* __restrict__ wb)
{
    const int u = blockIdx.x * 256 + threadIdx.x;
    if (u >= 638976) return;
    const float* s; short* d; int off;
    if      (u < 524288) { s = x;  d = xb;          off = u; }
    else if (u < 532480) { s = wf; d = wb;          off = u - 524288; }
    else if (u < 581632) { s = wq; d = wb + 65536;  off = u - 532480; }
    else if (u < 598016) { s = wo; d = wb + 458752; off = u - 581632; }
    else if (u < 614400) { s = w1; d = wb + 589824; off = u - 598016; }
    else if (u < 630784) { s = w2; d = wb + 720896; off = u - 614400; }
    else                 { s = wi; d = wb + 851968; off = u - 630784; }
    const float4 a = ((const float4*)s)[off * 2];
    const float4 b = ((const float4*)s)[off * 2 + 1];
    bf16x8 o;
    o[0] = f2bf(a.x); o[1] = f2bf(a.y); o[2] = f2bf(a.z); o[3] = f2bf(a.w);
    o[4] = f2bf(b.x); o[5] = f2bf(b.y); o[6] = f2bf(b.z); o[7] = f2bf(b.w);
    *(bf16x8*)(d + (size_t)off * 8) = o;
}

// ---------------------------------------------------------------------------
// bf16 MFMA GEMM (NT): C[m,n] = sum_k A[m,k]*W[n,k] + bias[n]
// 128x128 tile, BK=64, 256 thr, 16x16x32 MFMA, swizzled global_load_lds.
// FLAGS: 1=f32 out, 2=bf16 out, 4=relu, 8=qscale(first 256 cols).
// ---------------------------------------------------------------------------
template<int FLAGS>
__global__ __launch_bounds__(256) void gemm_bf16(const short* __restrict__ A,
                                                 const short* __restrict__ Bw,
                                                 const float* __restrict__ bias,
                                                 float* __restrict__ Cf,
                                                 short* __restrict__ Cb,
                                                 int M, int Nn, int K)
{
    __shared__ short Al[128 * 64];
    __shared__ short Bl[128 * 64];
    const int t = threadIdx.x, w = t >> 6, l = t & 63;
    const int lg = l >> 4, lr = l & 15;
    const int wm = w >> 1, wn = w & 1;
    const int m0 = blockIdx.x * 128, n0 = blockIdx.y * 128;
    const int srow = w * 32 + (l >> 3), sslot = l & 7;

    f32x4 acc[4][4] = {};

    for (int kb = 0; kb < K; kb += 64) {
        if (kb) __syncthreads();
        #pragma unroll
        for (int j = 0; j < 4; j++) {
            const int ra = srow + j * 8;
            const int sw = (sslot ^ (ra & 7)) << 3;
            gl_lds16(A  + (size_t)(m0 + ra) * K + kb + sw, &Al[(w * 32 + j * 8) * 64]);
            gl_lds16(Bw + (size_t)(n0 + ra) * K + kb + sw, &Bl[(w * 32 + j * 8) * 64]);
        }
        __syncthreads();
        #pragma unroll
        for (int ks = 0; ks < 2; ks++) {
            bf16x8 af[4], bfr[4];
            #pragma unroll
            for (int i = 0; i < 4; i++) {
                const int ar = wm * 64 + i * 16 + lr;
                af[i]  = *(const bf16x8*)&Al[ar * 64 + (((lg + ks * 4) ^ (ar & 7)) << 3)];
                const int br = wn * 64 + i * 16 + lr;
                bfr[i] = *(const bf16x8*)&Bl[br * 64 + (((lg + ks * 4) ^ (br & 7)) << 3)];
            }
            #pragma unroll
            for (int mi = 0; mi < 4; mi++)
                #pragma unroll
                for (int ni = 0; ni < 4; ni++)
                    acc[mi][ni] = __builtin_amdgcn_mfma_f32_16x16x32_bf16(af[mi], bfr[ni],
                                                                          acc[mi][ni], 0, 0, 0);
        }
    }

    #pragma unroll
    for (int ni = 0; ni < 4; ni++) {
        const int n = n0 + wn * 64 + ni * 16 + lr;
        const float bv = bias[n];
        const float qs = ((FLAGS & 8) && n < 256) ? 0.17677669529663687f : 1.0f;
        #pragma unroll
        for (int mi = 0; mi < 4; mi++) {
            #pragma unroll
            for (int r = 0; r < 4; r++) {
                const int m = m0 + wm * 64 + mi * 16 + 4 * lg + r;
                float v = (acc[mi][ni][r] + bv) * qs;
                if (FLAGS & 4) v = fmaxf(v, 0.f);
                if (FLAGS & 1) Cf[(size_t)m * Nn + n] = v;
                if (FLAGS & 2) Cb[(size_t)m * Nn + n] = f2bf(v);
            }
        }
    }
}

// ---------------------------------------------------------------------------
// BatchNorm over dim0, two-stage deterministic.
// ---------------------------------------------------------------------------
__global__ __launch_bounds__(256) void bn_partial(const float* __restrict__ Y,
                                                  float* __restrict__ part)
{
    const int t = threadIdx.x, blk = blockIdx.x;
    float s = 0.f, sq = 0.f;
    const float* p = Y + (size_t)blk * 256 * 256 + t;
    for (int r = 0; r < 256; r++) {
        float v = p[(size_t)r * 256];
        s += v; sq += v * v;
    }
    part[blk * 512 + t]       = s;
    part[blk * 512 + 256 + t] = sq;
}

__global__ __launch_bounds__(256) void bn_finalize(const float* __restrict__ part,
                                                   const float* __restrict__ g,
                                                   const float* __restrict__ b,
                                                   float* __restrict__ sc)
{
    const int t = threadIdx.x;
    float s = 0.f, sq = 0.f;
    for (int i = 0; i < 64; i++) { s += part[i * 512 + t]; sq += part[i * 512 + 256 + t]; }
    const float mean = s * (1.f / (float)ROWS);
    const float var  = sq * (1.f / (float)ROWS) - mean * mean;
    const float k    = g[t] * rsqrtf(var + EPS_);
    sc[t]       = k;
    sc[256 + t] = b[t] - mean * k;
}

__global__ __launch_bounds__(256) void bn_apply_leaky(const float* __restrict__ Y,
                                                      const float* __restrict__ sc,
                                                      float* __restrict__ O)
{
    const int idx = blockIdx.x * 256 + threadIdx.x;
    const int c4  = (idx & 63) * 4;
    const float4 v  = *(const float4*)&Y[(size_t)idx * 4];
    const float4 k  = *(const float4*)&sc[c4];
    const float4 sh = *(const float4*)&sc[256 + c4];
    float4 o;
    o.x = fmaf(v.x, k.x, sh.x); o.x = o.x >= 0.f ? o.x : 0.01f * o.x;
    o.y = fmaf(v.y, k.y, sh.y); o.y = o.y >= 0.f ? o.y : 0.01f * o.y;
    o.z = fmaf(v.z, k.z, sh.z); o.z = o.z >= 0.f ? o.z : 0.01f * o.z;
    o.w = fmaf(v.w, k.w, sh.w); o.w = o.w >= 0.f ? o.w : 0.01f * o.w;
    *(float4*)&O[(size_t)idx * 4] = o;
}

// ---------------------------------------------------------------------------
// Degree
// ---------------------------------------------------------------------------
__global__ __launch_bounds__(256) void deg_kernel(const int* __restrict__ adj,
                                                  int* __restrict__ deg)
{
    const int b = blockIdx.x;
    const int j = blockIdx.y * 256 + threadIdx.x;
    const int* p = adj + (size_t)b * N_ * N_ + j;
    int c = 0;
    for (int i = 0; i < N_; i++) c += (p[(size_t)i * N_] != 0);
    deg[b * N_ + j] = c;
}

// h += deg_emb[deg];  also emits bf16 copy of h
__global__ __launch_bounds__(256) void deg_add2(const int* __restrict__ deg,
                                                const float* __restrict__ emb,
                                                float* __restrict__ h,
                                                short* __restrict__ hb)
{
    const int idx = blockIdx.x * 256 + threadIdx.x;
    const int row = idx >> 6;
    const int c4  = (idx & 63) * 4;
    const int d   = deg[row];
    const float4 e = *(const float4*)&emb[(size_t)d * 256 + c4];
    float4 v = *(float4*)&h[(size_t)idx * 4];
    v.x += e.x; v.y += e.y; v.z += e.z; v.w += e.w;
    *(float4*)&h[(size_t)idx * 4] = v;
    short4 s; s.x = f2bf(v.x); s.y = f2bf(v.y); s.z = f2bf(v.z); s.w = f2bf(v.w);
    *(short4*)&hb[(size_t)idx * 4] = s;
}

// ---------------------------------------------------------------------------
// Residual + LayerNorm, writes h (f32) and hb (bf16)
// ---------------------------------------------------------------------------
__global__ __launch_bounds__(256) void add_ln2(float* __restrict__ h,
                                               short* __restrict__ hb,
                                               const float* __restrict__ p,
                                               const float* __restrict__ g,
                                               const float* __restrict__ be)
{
    const int wv = threadIdx.x >> 6, ln = threadIdx.x & 63;
    const size_t row  = (size_t)blockIdx.x * 4 + wv;
    const size_t base = row * 256 + ln * 4;
    const float4 a = *(const float4*)&h[base];
    const float4 q = *(const float4*)&p[base];
    const float v0 = a.x + q.x, v1 = a.y + q.y, v2 = a.z + q.z, v3 = a.w + q.w;
    float s  = v0 + v1 + v2 + v3;
    float sq = v0 * v0 + v1 * v1 + v2 * v2 + v3 * v3;
    #pragma unroll
    for (int m = 1; m < 64; m <<= 1) {
        s  += __shfl_xor(s,  m, 64);
        sq += __shfl_xor(sq, m, 64);
    }
    const float mean = s * (1.f / 256.f);
    const float var  = sq * (1.f / 256.f) - mean * mean;
    const float r    = rsqrtf(var + EPS_);
    const float4 gg = *(const float4*)&g[ln * 4];
    const float4 bb = *(const float4*)&be[ln * 4];
    float4 o;
    o.x = (v0 - mean) * r * gg.x + bb.x;
    o.y = (v1 - mean) * r * gg.y + bb.y;
    o.z = (v2 - mean) * r * gg.z + bb.z;
    o.w = (v3 - mean) * r * gg.w + bb.w;
    *(float4*)&h[base] = o;
    short4 sb; sb.x = f2bf(o.x); sb.y = f2bf(o.y); sb.z = f2bf(o.z); sb.w = f2bf(o.w);
    *(short4*)&hb[base] = sb;
}

// ---------------------------------------------------------------------------
// MFMA bf16 flash attention, SWAPPED-OPERAND form.
// S^T = mfma(K_frag, Q_frag, bias^T): C rows = k (4*lg+r), cols = q (lr).
// -> bias/spd lane access is spd[bs][q][k..k+3] = ONE int4 coalesced load.
// -> softmax state (m, l, alpha) is per-lane scalar (q = lr).
// O^T = mfma(V^T_frag, P^T_frag): C rows = d, cols = q -> short4 store.
// semb[:,ie] staged in LDS (100 floats).
// ---------------------------------------------------------------------------
#define KST 40    // K LDS row stride (bf16)
#define VST 136   // Vt LDS row stride
#define PST 136   // P LDS row stride (rows = q, 16 per wave)

__global__ __launch_bounds__(256) void attn_mfma(const short* __restrict__ qkv,
                                                 const int* __restrict__ spd,
                                                 const float* __restrict__ semb,
                                                 short* __restrict__ out)
{
    __shared__ short Kl[128 * KST];
    __shared__ short Vl[32 * VST];
    __shared__ short Pl[4][16 * PST];
    __shared__ float sembL[128];

    const int t  = threadIdx.x, w = t >> 6, l = t & 63;
    const int lg = l >> 4, lr = l & 15;

    const int s   = ((blockIdx.x & 7) << 7) + (blockIdx.x >> 3);
    const int bs  = s >> 5, ie = (s >> 2) & 7, qb = s & 3;
    const int b   = (ie * 32 + bs) >> 3, hd = (ie * 32 + bs) & 7;
    const int q0  = qb * 128 + w * 32;

    if (t < 100) sembL[t] = semb[t * 8 + ie];   // covered by first __syncthreads

    bf16x8 qf[2];
    #pragma unroll
    for (int qt = 0; qt < 2; qt++)
        qf[qt] = *(const bf16x8*)&qkv[((size_t)b * N_ + q0 + qt * 16 + lr) * 768 + hd * 32 + lg * 8];

    f32x4 oacc[2][2] = {};
    float mrun[2] = {-INFINITY, -INFINITY}, srun[2] = {0.f, 0.f};

    const int sr = t >> 1, shf = (t & 1) << 4;

    for (int k0 = 0; k0 < N_; k0 += 128) {
        if (k0) __syncthreads();
        {   // stage K [128][32] and V^T [32][128]
            const short* kg = qkv + ((size_t)b * N_ + k0 + sr) * 768 + 256 + hd * 32 + shf;
            *(bf16x8*)&Kl[sr * KST + shf]     = *(const bf16x8*)kg;
            *(bf16x8*)&Kl[sr * KST + shf + 8] = *(const bf16x8*)(kg + 8);
            const bf16x8 v0 = *(const bf16x8*)(kg + 256);
            const bf16x8 v1 = *(const bf16x8*)(kg + 264);
            #pragma unroll
            for (int i = 0; i < 8; i++) {
                Vl[(shf + i)     * VST + sr] = v0[i];
                Vl[(shf + 8 + i) * VST + sr] = v1[i];
            }
        }
        __syncthreads();

        bf16x8 kfr[8];
        #pragma unroll
        for (int ct = 0; ct < 8; ct++)
            kfr[ct] = *(const bf16x8*)&Kl[(ct * 16 + lr) * KST + lg * 8];
        bf16x8 vfr[4][2];
        #pragma unroll
        for (int kt = 0; kt < 4; kt++)
            #pragma unroll
            for (int c2 = 0; c2 < 2; c2++)
                vfr[kt][c2] = *(const bf16x8*)&Vl[(c2 * 16 + lr) * VST + kt * 32 + lg * 8];

        #pragma unroll
        for (int qt = 0; qt < 2; qt++) {
            // bias^T: lane (lg,lr) covers k = k0+ct*16+4lg..+3, q = q0+qt*16+lr
            const int4* sp4 = (const int4*)(spd + ((size_t)bs * N_ + q0 + qt * 16 + lr) * N_ + k0);
            f32x4 sA[8];
            #pragma unroll
            for (int ct = 0; ct < 8; ct++) {
                const int4 sv = sp4[ct * 4 + lg];
                f32x4 c;
                c[0] = (sv.x < 0) ? -1.0f : sembL[sv.x];
                c[1] = (sv.y < 0) ? -1.0f : sembL[sv.y];
                c[2] = (sv.z < 0) ? -1.0f : sembL[sv.z];
                c[3] = (sv.w < 0) ? -1.0f : sembL[sv.w];
                sA[ct] = c;
            }
            #pragma unroll
            for (int ct = 0; ct < 8; ct++)
                sA[ct] = __builtin_amdgcn_mfma_f32_16x16x32_bf16(kfr[ct], qf[qt], sA[ct], 0, 0, 0);

            // per-lane online softmax over the 32 k-values (q = lr)
            float m = sA[0][0];
            #pragma unroll
            for (int ct = 0; ct < 8; ct++)
                #pragma unroll
                for (int r = 0; r < 4; r++) m = fmaxf(m, sA[ct][r]);
            m = fmaxf(m, __shfl_xor(m, 16, 64));
            m = fmaxf(m, __shfl_xor(m, 32, 64));
            const float mnew  = fmaxf(mrun[qt], m);
            const float alpha = __expf(mrun[qt] - mnew);
            mrun[qt] = mnew;

            float ps = 0.f;
            #pragma unroll
            for (int ct = 0; ct < 8; ct++) {
                float p0 = __expf(sA[ct][0] - mnew);
                float p1 = __expf(sA[ct][1] - mnew);
                float p2 = __expf(sA[ct][2] - mnew);
                float p3 = __expf(sA[ct][3] - mnew);
                ps += (p0 + p1) + (p2 + p3);
                short4 pk; pk.x = f2bf(p0); pk.y = f2bf(p1); pk.z = f2bf(p2); pk.w = f2bf(p3);
                *(short4*)&Pl[w][lr * PST + ct * 16 + 4 * lg] = pk;   // [q][k], same-wave
            }
            ps += __shfl_xor(ps, 16, 64);
            ps += __shfl_xor(ps, 32, 64);
            srun[qt] = srun[qt] * alpha + ps;
            oacc[qt][0] *= alpha;
            oacc[qt][1] *= alpha;

            #pragma unroll
            for (int kt = 0; kt < 4; kt++) {
                const bf16x8 pa = *(const bf16x8*)&Pl[w][lr * PST + kt * 32 + lg * 8];
                #pragma unroll
                for (int c2 = 0; c2 < 2; c2++)
                    oacc[qt][c2] = __builtin_amdgcn_mfma_f32_16x16x32_bf16(vfr[kt][c2], pa,
                                                                           oacc[qt][c2], 0, 0, 0);
            }
        }
    }

    // O^T: lane holds (d = c2*16+4lg+r, q = lr) -> contiguous short4 per (qt,c2)
    #pragma unroll
    for (int qt = 0; qt < 2; qt++) {
        const float inv = 1.f / srun[qt];
        #pragma unroll
        for (int c2 = 0; c2 < 2; c2++) {
            short4 s4;
            s4.x = f2bf(oacc[qt][c2][0] * inv);
            s4.y = f2bf(oacc[qt][c2][1] * inv);
            s4.z = f2bf(oacc[qt][c2][2] * inv);
            s4.w = f2bf(oacc[qt][c2][3] * inv);
            *(short4*)&out[((size_t)b * N_ + q0 + qt * 16 + lr) * 256 + hd * 32 + c2 * 16 + 4 * lg] = s4;
        }
    }
}

// ---------------------------------------------------------------------------
extern "C" void kernel_launch(void* const* d_in, const int* in_sizes, int n_in,
                              void* d_out, int out_size, void* d_ws, size_t ws_size,
                              hipStream_t stream)
{
    const float* x    = (const float*)d_in[0];
    const int*   adj  = (const int*)  d_in[1];
    const int*   spd  = (const int*)  d_in[2];
    const float* Wf   = (const float*)d_in[3];
    const float* bf   = (const float*)d_in[4];
    const float* bn1g = (const float*)d_in[5];
    const float* bn1b = (const float*)d_in[6];
    const float* degE = (const float*)d_in[7];
    const float* semb = (const float*)d_in[8];
    const float* Wqkv = (const float*)d_in[9];
    const float* bqkv = (const float*)d_in[10];
    const float* Wo   = (const float*)d_in[11];
    const float* bo   = (const float*)d_in[12];
    const float* ln1g = (const float*)d_in[13];
    const float* ln1b = (const float*)d_in[14];
    const float* W1   = (const float*)d_in[15];
    const float* b1   = (const float*)d_in[16];
    const float* W2   = (const float*)d_in[17];
    const float* b2   = (const float*)d_in[18];
    const float* ln2g = (const float*)d_in[19];
    const float* ln2b = (const float*)d_in[20];
    const float* Win  = (const float*)d_in[21];
    const float* bin  = (const float*)d_in[22];
    const float* bn2g = (const float*)d_in[23];
    const float* bn2b = (const float*)d_in[24];

    char* p = (char*)d_ws;
    float* h    = (float*)p;  p += (size_t)ROWS * 256 * 4;
    float* t3   = (float*)p;  p += (size_t)ROWS * 256 * 4;
    char*  shr  = p;          p += (size_t)ROWS * 768 * 2;   // t1(f32) / qkvb(bf16)
    float* t1   = (float*)shr;
    short* qkvb = (short*)shr;
    short* hb   = (short*)p;  p += (size_t)ROWS * 256 * 2;
    short* t2b  = (short*)p;  p += (size_t)ROWS * 256 * 2;
    short* xb   = (short*)p;  p += (size_t)ROWS * 256 * 2;
    short* wb   = (short*)p;  p += (size_t)917504 * 2;
    int*   deg  = (int*)p;    p += (size_t)ROWS * 4;
    float* bnp  = (float*)p;  p += 64 * 512 * 4;
    float* bnf  = (float*)p;

    const short* wfb = wb;
    const short* wqb = wb + 65536;
    const short* wob = wb + 458752;
    const short* w1b = wb + 589824;
    const short* w2b = wb + 720896;
    const short* wib = wb + 851968;

    const dim3 blk(256);
    const dim3 g256(128, 2);    // M/128 x 256/128
    const dim3 g768(128, 6);    // M/128 x 768/128

    cvt_all<<<2496, blk, 0, stream>>>(x, Wf, Wqkv, Wo, W1, W2, Win, xb, wb);

    // 1. lin_first
    gemm_bf16<1><<<g256, blk, 0, stream>>>(xb, wfb, bf, t1, nullptr, ROWS, 256, 256);
    bn_partial <<<64, blk, 0, stream>>>(t1, bnp);
    bn_finalize<<<1,  blk, 0, stream>>>(bnp, bn1g, bn1b, bnf);
    bn_apply_leaky<<<ROWS * 256 / 4 / 256, blk, 0, stream>>>(t1, bnf, h);

    // 2. degree embedding
    deg_kernel<<<dim3(B_, N_ / 256), blk, 0, stream>>>(adj, deg);
    deg_add2  <<<ROWS * 256 / 4 / 256, blk, 0, stream>>>(deg, degE, h, hb);

    // 3. transformer layers
    for (int l = 0; l < L_; l++) {
        gemm_bf16<2 | 8><<<g768, blk, 0, stream>>>(hb, wqb + (size_t)l * 768 * 256,
                                                   bqkv + l * 768, nullptr, qkvb, ROWS, 768, 256);
        attn_mfma<<<1024, blk, 0, stream>>>(qkvb, spd, semb, t2b);
        gemm_bf16<1><<<g256, blk, 0, stream>>>(t2b, wob + (size_t)l * 256 * 256,
                                               bo + l * 256, t3, nullptr, ROWS, 256, 256);
        add_ln2<<<ROWS / 4, blk, 0, stream>>>(h, hb, t3, ln1g + l * 256, ln1b + l * 256);
        gemm_bf16<2 | 4><<<g256, blk, 0, stream>>>(hb, w1b + (size_t)l * 256 * 256,
                                                   b1 + l * 256, nullptr, t2b, ROWS, 256, 256);
        gemm_bf16<1><<<g256, blk, 0, stream>>>(t2b, w2b + (size_t)l * 256 * 256,
                                               b2 + l * 256, t3, nullptr, ROWS, 256, 256);
        add_ln2<<<ROWS / 4, blk, 0, stream>>>(h, hb, t3, ln2g + l * 256, ln2b + l * 256);
    }

    // 4. lin_in
    gemm_bf16<1><<<g256, blk, 0, stream>>>(hb, wib, bin, t1, nullptr, ROWS, 256, 256);
    bn_partial <<<64, blk, 0, stream>>>(t1, bnp);
    bn_finalize<<<1,  blk, 0, stream>>>(bnp, bn2g, bn2b, bnf);
    bn_apply_leaky<<<ROWS * 256 / 4 / 256, blk, 0, stream>>>(t1, bnf, (float*)d_out);
}

// Round 6
// 493.540 us; speedup vs baseline: 3.3741x; 1.0352x over previous
//
#include <hip/hip_runtime.h>
#include <hip/hip_bf16.h>
#include <math.h>

#define B_   32
#define N_   512
#define D_   256
#define H_   8
#define DH_  32
#define L_   2
#define ROWS (B_ * N_)          // 16384
#define EPS_ 1e-5f

typedef __attribute__((ext_vector_type(8))) short bf16x8;
typedef __attribute__((ext_vector_type(4))) float f32x4;

__device__ __forceinline__ short f2bf(float f) {
    unsigned u = __builtin_bit_cast(unsigned, f);
    u += 0x7fffu + ((u >> 16) & 1u);          // round-to-nearest-even
    return (short)(u >> 16);
}

__device__ __forceinline__ void gl_lds16(const short* g, short* l) {
    __builtin_amdgcn_global_load_lds(
        (const __attribute__((address_space(1))) unsigned int*)g,
        (__attribute__((address_space(3))) unsigned int*)l, 16, 0, 0);
}

// ---------------------------------------------------------------------------
// One-shot f32 -> bf16 conversion of x and all GEMM weights.
// ---------------------------------------------------------------------------
__global__ __launch_bounds__(256) void cvt_all(const float* __restrict__ x,
                                               const float* __restrict__ wf,
                                               const float* __restrict__ wq,
                                               const float* __restrict__ wo,
                                               const float* __restrict__ w1,
                                               const float* __restrict__ w2,
                                               const float* __restrict__ wi,
                                               short* __restrict__ xb,
                                               short* __restrict__ wb)
{
    const int u = blockIdx.x * 256 + threadIdx.x;
    if (u >= 638976) return;
    const float* s; short* d; int off;
    if      (u < 524288) { s = x;  d = xb;          off = u; }
    else if (u < 532480) { s = wf; d = wb;          off = u - 524288; }
    else if (u < 581632) { s = wq; d = wb + 65536;  off = u - 532480; }
    else if (u < 598016) { s = wo; d = wb + 458752; off = u - 581632; }
    else if (u < 614400) { s = w1; d = wb + 589824; off = u - 598016; }
    else if (u < 630784) { s = w2; d = wb + 720896; off = u - 614400; }
    else                 { s = wi; d = wb + 851968; off = u - 630784; }
    const float4 a = ((const float4*)s)[off * 2];
    const float4 b = ((const float4*)s)[off * 2 + 1];
    bf16x8 o;
    o[0] = f2bf(a.x); o[1] = f2bf(a.y); o[2] = f2bf(a.z); o[3] = f2bf(a.w);
    o[4] = f2bf(b.x); o[5] = f2bf(b.y); o[6] = f2bf(b.z); o[7] = f2bf(b.w);
    *(bf16x8*)(d + (size_t)off * 8) = o;
}

// ---------------------------------------------------------------------------
// bf16 MFMA GEMM (NT), 2-phase double-buffered LDS pipeline.
// 128x128 tile, BK=64, 256 thr, 16x16x32 MFMA, swizzled global_load_lds.
// FLAGS: 1=f32 out, 2=bf16 out, 4=relu, 8=qscale(first 256 cols).
// ---------------------------------------------------------------------------
#define GSTAGE(buf, kb)                                                        \
    {                                                                          \
        _Pragma("unroll")                                                      \
        for (int j = 0; j < 4; j++) {                                          \
            const int ra = srow + j * 8;                                       \
            const int sw = (sslot ^ (ra & 7)) << 3;                            \
            gl_lds16(A  + (size_t)(m0 + ra) * K + (kb) + sw,                   \
                     &Al[buf][(w * 32 + j * 8) * 64]);                         \
            gl_lds16(Bw + (size_t)(n0 + ra) * K + (kb) + sw,                   \
                     &Bl[buf][(w * 32 + j * 8) * 64]);                         \
        }                                                                      \
    }

template<int FLAGS>
__global__ __launch_bounds__(256) void gemm_bf16(const short* __restrict__ A,
                                                 const short* __restrict__ Bw,
                                                 const float* __restrict__ bias,
                                                 float* __restrict__ Cf,
                                                 short* __restrict__ Cb,
                                                 int M, int Nn, int K)
{
    __shared__ short Al[2][128 * 64];
    __shared__ short Bl[2][128 * 64];
    const int t = threadIdx.x, w = t >> 6, l = t & 63;
    const int lg = l >> 4, lr = l & 15;
    const int wm = w >> 1, wn = w & 1;
    const int m0 = blockIdx.x * 128, n0 = blockIdx.y * 128;
    const int srow = w * 32 + (l >> 3), sslot = l & 7;

    f32x4 acc[4][4] = {};

    GSTAGE(0, 0);
    __syncthreads();                       // auto vmcnt(0) drain
    int cur = 0;
    for (int kb = 64; kb < K + 64; kb += 64) {
        if (kb < K) GSTAGE(cur ^ 1, kb);   // prefetch next tile
        #pragma unroll
        for (int ks = 0; ks < 2; ks++) {
            bf16x8 af[4], bfr[4];
            #pragma unroll
            for (int i = 0; i < 4; i++) {
                const int ar = wm * 64 + i * 16 + lr;
                af[i]  = *(const bf16x8*)&Al[cur][ar * 64 + (((lg + ks * 4) ^ (ar & 7)) << 3)];
                const int br = wn * 64 + i * 16 + lr;
                bfr[i] = *(const bf16x8*)&Bl[cur][br * 64 + (((lg + ks * 4) ^ (br & 7)) << 3)];
            }
            #pragma unroll
            for (int mi = 0; mi < 4; mi++)
                #pragma unroll
                for (int ni = 0; ni < 4; ni++)
                    acc[mi][ni] = __builtin_amdgcn_mfma_f32_16x16x32_bf16(af[mi], bfr[ni],
                                                                          acc[mi][ni], 0, 0, 0);
        }
        __syncthreads();                   // drains the prefetch loads too
        cur ^= 1;
    }

    #pragma unroll
    for (int ni = 0; ni < 4; ni++) {
        const int n = n0 + wn * 64 + ni * 16 + lr;
        const float bv = bias[n];
        const float qs = ((FLAGS & 8) && n < 256) ? 0.17677669529663687f : 1.0f;
        #pragma unroll
        for (int mi = 0; mi < 4; mi++) {
            #pragma unroll
            for (int r = 0; r < 4; r++) {
                const int m = m0 + wm * 64 + mi * 16 + 4 * lg + r;
                float v = (acc[mi][ni][r] + bv) * qs;
                if (FLAGS & 4) v = fmaxf(v, 0.f);
                if (FLAGS & 1) Cf[(size_t)m * Nn + n] = v;
                if (FLAGS & 2) Cb[(size_t)m * Nn + n] = f2bf(v);
            }
        }
    }
}

// ---------------------------------------------------------------------------
// BatchNorm stats, two-stage deterministic. Partial layout TRANSPOSED:
// part[t*64 + blk] so finalize does contiguous float4 loads per column.
// ---------------------------------------------------------------------------
__global__ __launch_bounds__(256) void bn_partial(const float* __restrict__ Y,
                                                  float* __restrict__ part)
{
    const int t = threadIdx.x, blk = blockIdx.x;
    float s = 0.f, sq = 0.f;
    const float* p = Y + (size_t)blk * 256 * 256 + t;
    for (int r = 0; r < 256; r++) {
        float v = p[(size_t)r * 256];
        s += v; sq += v * v;
    }
    part[t * 64 + blk]         = s;
    part[16384 + t * 64 + blk] = sq;
}

__global__ __launch_bounds__(256) void bn_finalize(const float* __restrict__ part,
                                                   const float* __restrict__ g,
                                                   const float* __restrict__ b,
                                                   float* __restrict__ sc)
{
    const int t = threadIdx.x;
    float s = 0.f, sq = 0.f;
    #pragma unroll
    for (int i = 0; i < 16; i++) {
        const float4 a = *(const float4*)&part[t * 64 + i * 4];
        const float4 q = *(const float4*)&part[16384 + t * 64 + i * 4];
        s  += (a.x + a.y) + (a.z + a.w);
        sq += (q.x + q.y) + (q.z + q.w);
    }
    const float mean = s * (1.f / (float)ROWS);
    const float var  = sq * (1.f / (float)ROWS) - mean * mean;
    const float k    = g[t] * rsqrtf(var + EPS_);
    sc[t]       = k;
    sc[256 + t] = b[t] - mean * k;
}

// final-output BN apply (no degree add)
__global__ __launch_bounds__(256) void bn_apply_leaky(const float* __restrict__ Y,
                                                      const float* __restrict__ sc,
                                                      float* __restrict__ O)
{
    const int idx = blockIdx.x * 256 + threadIdx.x;
    const int c4  = (idx & 63) * 4;
    const float4 v  = *(const float4*)&Y[(size_t)idx * 4];
    const float4 k  = *(const float4*)&sc[c4];
    const float4 sh = *(const float4*)&sc[256 + c4];
    float4 o;
    o.x = fmaf(v.x, k.x, sh.x); o.x = o.x >= 0.f ? o.x : 0.01f * o.x;
    o.y = fmaf(v.y, k.y, sh.y); o.y = o.y >= 0.f ? o.y : 0.01f * o.y;
    o.z = fmaf(v.z, k.z, sh.z); o.z = o.z >= 0.f ? o.z : 0.01f * o.z;
    o.w = fmaf(v.w, k.w, sh.w); o.w = o.w >= 0.f ? o.w : 0.01f * o.w;
    *(float4*)&O[(size_t)idx * 4] = o;
}

// fused: h = leaky(bn(Y)) + deg_emb[deg]; writes h (f32) + hb (bf16)
__global__ __launch_bounds__(256) void bn_deg(const float* __restrict__ Y,
                                              const float* __restrict__ sc,
                                              const int* __restrict__ deg,
                                              const float* __restrict__ emb,
                                              float* __restrict__ h,
                                              short* __restrict__ hb)
{
    const int idx = blockIdx.x * 256 + threadIdx.x;
    const int row = idx >> 6;
    const int c4  = (idx & 63) * 4;
    const float4 v  = *(const float4*)&Y[(size_t)idx * 4];
    const float4 k  = *(const float4*)&sc[c4];
    const float4 sh = *(const float4*)&sc[256 + c4];
    const int d = deg[row];
    const float4 e = *(const float4*)&emb[(size_t)d * 256 + c4];
    float4 o;
    o.x = fmaf(v.x, k.x, sh.x); o.x = (o.x >= 0.f ? o.x : 0.01f * o.x) + e.x;
    o.y = fmaf(v.y, k.y, sh.y); o.y = (o.y >= 0.f ? o.y : 0.01f * o.y) + e.y;
    o.z = fmaf(v.z, k.z, sh.z); o.z = (o.z >= 0.f ? o.z : 0.01f * o.z) + e.z;
    o.w = fmaf(v.w, k.w, sh.w); o.w = (o.w >= 0.f ? o.w : 0.01f * o.w) + e.w;
    *(float4*)&h[(size_t)idx * 4] = o;
    short4 s4; s4.x = f2bf(o.x); s4.y = f2bf(o.y); s4.z = f2bf(o.z); s4.w = f2bf(o.w);
    *(short4*)&hb[(size_t)idx * 4] = s4;
}

// ---------------------------------------------------------------------------
// Degree: 256 blocks (32 b x 8 col-groups), 4 row-groups + LDS reduce.
// ---------------------------------------------------------------------------
__global__ __launch_bounds__(256) void deg_kernel(const int* __restrict__ adj,
                                                  int* __restrict__ deg)
{
    __shared__ int sm[4][64];
    const int b = blockIdx.x, j0 = blockIdx.y * 64;
    const int tg = threadIdx.x >> 6, lane = threadIdx.x & 63;
    const int* p = adj + (size_t)b * N_ * N_ + j0 + lane;
    int c = 0;
    #pragma unroll 4
    for (int i = tg; i < N_; i += 4) c += (p[(size_t)i * N_] != 0);
    sm[tg][lane] = c;
    __syncthreads();
    if (threadIdx.x < 64)
        deg[b * N_ + j0 + threadIdx.x] =
            sm[0][threadIdx.x] + sm[1][threadIdx.x] + sm[2][threadIdx.x] + sm[3][threadIdx.x];
}

// ---------------------------------------------------------------------------
// Residual + LayerNorm, writes h (f32) and hb (bf16)
// ---------------------------------------------------------------------------
__global__ __launch_bounds__(256) void add_ln2(float* __restrict__ h,
                                               short* __restrict__ hb,
                                               const float* __restrict__ p,
                                               const float* __restrict__ g,
                                               const float* __restrict__ be)
{
    const int wv = threadIdx.x >> 6, ln = threadIdx.x & 63;
    const size_t row  = (size_t)blockIdx.x * 4 + wv;
    const size_t base = row * 256 + ln * 4;
    const float4 a = *(const float4*)&h[base];
    const float4 q = *(const float4*)&p[base];
    const float v0 = a.x + q.x, v1 = a.y + q.y, v2 = a.z + q.z, v3 = a.w + q.w;
    float s  = v0 + v1 + v2 + v3;
    float sq = v0 * v0 + v1 * v1 + v2 * v2 + v3 * v3;
    #pragma unroll
    for (int m = 1; m < 64; m <<= 1) {
        s  += __shfl_xor(s,  m, 64);
        sq += __shfl_xor(sq, m, 64);
    }
    const float mean = s * (1.f / 256.f);
    const float var  = sq * (1.f / 256.f) - mean * mean;
    const float r    = rsqrtf(var + EPS_);
    const float4 gg = *(const float4*)&g[ln * 4];
    const float4 bb = *(const float4*)&be[ln * 4];
    float4 o;
    o.x = (v0 - mean) * r * gg.x + bb.x;
    o.y = (v1 - mean) * r * gg.y + bb.y;
    o.z = (v2 - mean) * r * gg.z + bb.z;
    o.w = (v3 - mean) * r * gg.w + bb.w;
    *(float4*)&h[base] = o;
    short4 sb; sb.x = f2bf(o.x); sb.y = f2bf(o.y); sb.z = f2bf(o.z); sb.w = f2bf(o.w);
    *(short4*)&hb[base] = sb;
}

// ---------------------------------------------------------------------------
// MFMA bf16 flash attention, swapped-operand form + async-STAGE split:
// next tile's K/V loaded global->reg right after fragment reads (latency
// hides under QK/softmax/PV), LDS write deferred to after the compute barrier.
// V^T rows offset by (d>>4)*32 shorts to halve staging write conflicts.
// ---------------------------------------------------------------------------
#define KST 40    // K LDS row stride (bf16)
#define VST 136   // Vt LDS row stride (+32-short offset per 16-row half)
#define PST 136   // P LDS row stride

__global__ __launch_bounds__(256) void attn_mfma(const short* __restrict__ qkv,
                                                 const int* __restrict__ spd,
                                                 const float* __restrict__ semb,
                                                 short* __restrict__ out)
{
    __shared__ short Kl[128 * KST];
    __shared__ short Vl[32 * VST + 64];
    __shared__ short Pl[4][16 * PST];
    __shared__ float sembL[128];

    const int t  = threadIdx.x, w = t >> 6, l = t & 63;
    const int lg = l >> 4, lr = l & 15;

    const int s   = ((blockIdx.x & 7) << 7) + (blockIdx.x >> 3);
    const int bs  = s >> 5, ie = (s >> 2) & 7, qb = s & 3;
    const int b   = (ie * 32 + bs) >> 3, hd = (ie * 32 + bs) & 7;
    const int q0  = qb * 128 + w * 32;

    if (t < 100) sembL[t] = semb[t * 8 + ie];

    bf16x8 qf[2];
    #pragma unroll
    for (int qt = 0; qt < 2; qt++)
        qf[qt] = *(const bf16x8*)&qkv[((size_t)b * N_ + q0 + qt * 16 + lr) * 768 + hd * 32 + lg * 8];

    f32x4 oacc[2][2] = {};
    float mrun[2] = {-INFINITY, -INFINITY}, srun[2] = {0.f, 0.f};

    const int sr = t >> 1, shf = (t & 1) << 4;
    const int vofs = (t & 1) * 32;                  // (d>>4)*32 for this lane's rows
    const short* kgBase = qkv + ((size_t)b * N_ + sr) * 768 + 256 + hd * 32 + shf;

    // prologue: stage tile 0
    bf16x8 nk0 = *(const bf16x8*)(kgBase);
    bf16x8 nk1 = *(const bf16x8*)(kgBase + 8);
    bf16x8 nv0 = *(const bf16x8*)(kgBase + 256);
    bf16x8 nv1 = *(const bf16x8*)(kgBase + 264);
    *(bf16x8*)&Kl[sr * KST + shf]     = nk0;
    *(bf16x8*)&Kl[sr * KST + shf + 8] = nk1;
    #pragma unroll
    for (int i = 0; i < 8; i++) {
        Vl[(shf + i)     * VST + vofs + sr] = nv0[i];
        Vl[(shf + 8 + i) * VST + vofs + sr] = nv1[i];
    }
    __syncthreads();

    for (int ti = 0; ti < 4; ti++) {
        const int k0 = ti * 128;
        // fragments from LDS
        bf16x8 kfr[8];
        #pragma unroll
        for (int ct = 0; ct < 8; ct++)
            kfr[ct] = *(const bf16x8*)&Kl[(ct * 16 + lr) * KST + lg * 8];
        bf16x8 vfr[4][2];
        #pragma unroll
        for (int kt = 0; kt < 4; kt++)
            #pragma unroll
            for (int c2 = 0; c2 < 2; c2++)
                vfr[kt][c2] = *(const bf16x8*)&Vl[(c2 * 16 + lr) * VST + c2 * 32 + kt * 32 + lg * 8];

        // async prefetch of next tile (wraps on last iter; harmless)
        const short* kgN = kgBase + (size_t)(((ti + 1) & 3) * 128) * 768;
        nk0 = *(const bf16x8*)(kgN);
        nk1 = *(const bf16x8*)(kgN + 8);
        nv0 = *(const bf16x8*)(kgN + 256);
        nv1 = *(const bf16x8*)(kgN + 264);

        #pragma unroll
        for (int qt = 0; qt < 2; qt++) {
            const int4* sp4 = (const int4*)(spd + ((size_t)bs * N_ + q0 + qt * 16 + lr) * N_ + k0);
            f32x4 sA[8];
            #pragma unroll
            for (int ct = 0; ct < 8; ct++) {
                const int4 sv = sp4[ct * 4 + lg];
                f32x4 c;
                c[0] = (sv.x < 0) ? -1.0f : sembL[sv.x];
                c[1] = (sv.y < 0) ? -1.0f : sembL[sv.y];
                c[2] = (sv.z < 0) ? -1.0f : sembL[sv.z];
                c[3] = (sv.w < 0) ? -1.0f : sembL[sv.w];
                sA[ct] = c;
            }
            #pragma unroll
            for (int ct = 0; ct < 8; ct++)
                sA[ct] = __builtin_amdgcn_mfma_f32_16x16x32_bf16(kfr[ct], qf[qt], sA[ct], 0, 0, 0);

            float m = sA[0][0];
            #pragma unroll
            for (int ct = 0; ct < 8; ct++)
                #pragma unroll
                for (int r = 0; r < 4; r++) m = fmaxf(m, sA[ct][r]);
            m = fmaxf(m, __shfl_xor(m, 16, 64));
            m = fmaxf(m, __shfl_xor(m, 32, 64));
            const float mnew  = fmaxf(mrun[qt], m);
            const float alpha = __expf(mrun[qt] - mnew);
            mrun[qt] = mnew;

            float ps = 0.f;
            #pragma unroll
            for (int ct = 0; ct < 8; ct++) {
                float p0 = __expf(sA[ct][0] - mnew);
                float p1 = __expf(sA[ct][1] - mnew);
                float p2 = __expf(sA[ct][2] - mnew);
                float p3 = __expf(sA[ct][3] - mnew);
                ps += (p0 + p1) + (p2 + p3);
                short4 pk; pk.x = f2bf(p0); pk.y = f2bf(p1); pk.z = f2bf(p2); pk.w = f2bf(p3);
                *(short4*)&Pl[w][lr * PST + ct * 16 + 4 * lg] = pk;
            }
            ps += __shfl_xor(ps, 16, 64);
            ps += __shfl_xor(ps, 32, 64);
            srun[qt] = srun[qt] * alpha + ps;
            oacc[qt][0] *= alpha;
            oacc[qt][1] *= alpha;

            #pragma unroll
            for (int kt = 0; kt < 4; kt++) {
                const bf16x8 pa = *(const bf16x8*)&Pl[w][lr * PST + kt * 32 + lg * 8];
                #pragma unroll
                for (int c2 = 0; c2 < 2; c2++)
                    oacc[qt][c2] = __builtin_amdgcn_mfma_f32_16x16x32_bf16(vfr[kt][c2], pa,
                                                                           oacc[qt][c2], 0, 0, 0);
            }
        }

        if (ti < 3) {   // write prefetched tile to LDS
            __syncthreads();
            *(bf16x8*)&Kl[sr * KST + shf]     = nk0;
            *(bf16x8*)&Kl[sr * KST + shf + 8] = nk1;
            #pragma unroll
            for (int i = 0; i < 8; i++) {
                Vl[(shf + i)     * VST + vofs + sr] = nv0[i];
                Vl[(shf + 8 + i) * VST + vofs + sr] = nv1[i];
            }
            __syncthreads();
        }
    }

    #pragma unroll
    for (int qt = 0; qt < 2; qt++) {
        const float inv = 1.f / srun[qt];
        #pragma unroll
        for (int c2 = 0; c2 < 2; c2++) {
            short4 s4;
            s4.x = f2bf(oacc[qt][c2][0] * inv);
            s4.y = f2bf(oacc[qt][c2][1] * inv);
            s4.z = f2bf(oacc[qt][c2][2] * inv);
            s4.w = f2bf(oacc[qt][c2][3] * inv);
            *(short4*)&out[((size_t)b * N_ + q0 + qt * 16 + lr) * 256 + hd * 32 + c2 * 16 + 4 * lg] = s4;
        }
    }
}

// ---------------------------------------------------------------------------
extern "C" void kernel_launch(void* const* d_in, const int* in_sizes, int n_in,
                              void* d_out, int out_size, void* d_ws, size_t ws_size,
                              hipStream_t stream)
{
    const float* x    = (const float*)d_in[0];
    const int*   adj  = (const int*)  d_in[1];
    const int*   spd  = (const int*)  d_in[2];
    const float* Wf   = (const float*)d_in[3];
    const float* bf   = (const float*)d_in[4];
    const float* bn1g = (const float*)d_in[5];
    const float* bn1b = (const float*)d_in[6];
    const float* degE = (const float*)d_in[7];
    const float* semb = (const float*)d_in[8];
    const float* Wqkv = (const float*)d_in[9];
    const float* bqkv = (const float*)d_in[10];
    const float* Wo   = (const float*)d_in[11];
    const float* bo   = (const float*)d_in[12];
    const float* ln1g = (const float*)d_in[13];
    const float* ln1b = (const float*)d_in[14];
    const float* W1   = (const float*)d_in[15];
    const float* b1   = (const float*)d_in[16];
    const float* W2   = (const float*)d_in[17];
    const float* b2   = (const float*)d_in[18];
    const float* ln2g = (const float*)d_in[19];
    const float* ln2b = (const float*)d_in[20];
    const float* Win  = (const float*)d_in[21];
    const float* bin  = (const float*)d_in[22];
    const float* bn2g = (const float*)d_in[23];
    const float* bn2b = (const float*)d_in[24];

    char* p = (char*)d_ws;
    float* h    = (float*)p;  p += (size_t)ROWS * 256 * 4;
    float* t3   = (float*)p;  p += (size_t)ROWS * 256 * 4;
    char*  shr  = p;          p += (size_t)ROWS * 768 * 2;   // t1(f32) / qkvb(bf16)
    float* t1   = (float*)shr;
    short* qkvb = (short*)shr;
    short* hb   = (short*)p;  p += (size_t)ROWS * 256 * 2;
    short* t2b  = (short*)p;  p += (size_t)ROWS * 256 * 2;
    short* xb   = (short*)p;  p += (size_t)ROWS * 256 * 2;
    short* wb   = (short*)p;  p += (size_t)917504 * 2;
    int*   deg  = (int*)p;    p += (size_t)ROWS * 4;
    float* bnp  = (float*)p;  p += 64 * 512 * 4;
    float* bnf  = (float*)p;

    const short* wfb = wb;
    const short* wqb = wb + 65536;
    const short* wob = wb + 458752;
    const short* w1b = wb + 589824;
    const short* w2b = wb + 720896;
    const short* wib = wb + 851968;

    const dim3 blk(256);
    const dim3 g256(128, 2);    // M/128 x 256/128
    const dim3 g768(128, 6);    // M/128 x 768/128

    cvt_all<<<2496, blk, 0, stream>>>(x, Wf, Wqkv, Wo, W1, W2, Win, xb, wb);
    deg_kernel<<<dim3(B_, 8), blk, 0, stream>>>(adj, deg);

    // 1. lin_first + BN + leaky + degree add (fused apply)
    gemm_bf16<1><<<g256, blk, 0, stream>>>(xb, wfb, bf, t1, nullptr, ROWS, 256, 256);
    bn_partial <<<64, blk, 0, stream>>>(t1, bnp);
    bn_finalize<<<1,  blk, 0, stream>>>(bnp, bn1g, bn1b, bnf);
    bn_deg<<<ROWS * 256 / 4 / 256, blk, 0, stream>>>(t1, bnf, deg, degE, h, hb);

    // 2. transformer layers
    for (int l = 0; l < L_; l++) {
        gemm_bf16<2 | 8><<<g768, blk, 0, stream>>>(hb, wqb + (size_t)l * 768 * 256,
                                                   bqkv + l * 768, nullptr, qkvb, ROWS, 768, 256);
        attn_mfma<<<1024, blk, 0, stream>>>(qkvb, spd, semb, t2b);
        gemm_bf16<1><<<g256, blk, 0, stream>>>(t2b, wob + (size_t)l * 256 * 256,
                                               bo + l * 256, t3, nullptr, ROWS, 256, 256);
        add_ln2<<<ROWS / 4, blk, 0, stream>>>(h, hb, t3, ln1g + l * 256, ln1b + l * 256);
        gemm_bf16<2 | 4><<<g256, blk, 0, stream>>>(hb, w1b + (size_t)l * 256 * 256,
                                                   b1 + l * 256, nullptr, t2b, ROWS, 256, 256);
        gemm_bf16<1><<<g256, blk, 0, stream>>>(t2b, w2b + (size_t)l * 256 * 256,
                                               b2 + l * 256, t3, nullptr, ROWS, 256, 256);
        add_ln2<<<ROWS / 4, blk, 0, stream>>>(h, hb, t3, ln2g + l * 256, ln2b + l * 256);
    }

    // 3. lin_in + BN + leaky -> out
    gemm_bf16<1><<<g256, blk, 0, stream>>>(hb, wib, bin, t1, nullptr, ROWS, 256, 256);
    bn_partial <<<64, blk, 0, stream>>>(t1, bnp);
    bn_finalize<<<1,  blk, 0, stream>>>(bnp, bn2g, bn2b, bnf);
    bn_apply_leaky<<<ROWS * 256 / 4 / 256, blk, 0, stream>>>(t1, bnf, (float*)d_out);
}

// Round 7
// 488.874 us; speedup vs baseline: 3.4063x; 1.0095x over previous
//
#include <hip/hip_runtime.h>
#include <hip/hip_bf16.h>
#include <math.h>

#define B_   32
#define N_   512
#define D_   256
#define H_   8
#define DH_  32
#define L_   2
#define ROWS (B_ * N_)          // 16384
#define EPS_ 1e-5f

typedef __attribute__((ext_vector_type(8))) short bf16x8;
typedef __attribute__((ext_vector_type(4))) float f32x4;

__device__ __forceinline__ short f2bf(float f) {
    unsigned u = __builtin_bit_cast(unsigned, f);
    u += 0x7fffu + ((u >> 16) & 1u);          // round-to-nearest-even
    return (short)(u >> 16);
}

// v_cvt_pk_bf16_f32: 2 f32 -> 2 bf16 (RTNE) in one u32
__device__ __forceinline__ unsigned cvtpk(float lo, float hi) {
    unsigned r;
    asm("v_cvt_pk_bf16_f32 %0, %1, %2" : "=v"(r) : "v"(lo), "v"(hi));
    return r;
}

__device__ __forceinline__ void gl_lds16(const short* g, short* l) {
    __builtin_amdgcn_global_load_lds(
        (const __attribute__((address_space(1))) unsigned int*)g,
        (__attribute__((address_space(3))) unsigned int*)l, 16, 0, 0);
}

// ---------------------------------------------------------------------------
// One-shot f32 -> bf16 conversion of x and all GEMM weights.
// ---------------------------------------------------------------------------
__global__ __launch_bounds__(256) void cvt_all(const float* __restrict__ x,
                                               const float* __restrict__ wf,
                                               const float* __restrict__ wq,
                                               const float* __restrict__ wo,
                                               const float* __restrict__ w1,
                                               const float* __restrict__ w2,
                                               const float* __restrict__ wi,
                                               short* __restrict__ xb,
                                               short* __restrict__ wb)
{
    const int u = blockIdx.x * 256 + threadIdx.x;
    if (u >= 638976) return;
    const float* s; short* d; int off;
    if      (u < 524288) { s = x;  d = xb;          off = u; }
    else if (u < 532480) { s = wf; d = wb;          off = u - 524288; }
    else if (u < 581632) { s = wq; d = wb + 65536;  off = u - 532480; }
    else if (u < 598016) { s = wo; d = wb + 458752; off = u - 581632; }
    else if (u < 614400) { s = w1; d = wb + 589824; off = u - 598016; }
    else if (u < 630784) { s = w2; d = wb + 720896; off = u - 614400; }
    else                 { s = wi; d = wb + 851968; off = u - 630784; }
    const float4 a = ((const float4*)s)[off * 2];
    const float4 b = ((const float4*)s)[off * 2 + 1];
    bf16x8 o;
    o[0] = f2bf(a.x); o[1] = f2bf(a.y); o[2] = f2bf(a.z); o[3] = f2bf(a.w);
    o[4] = f2bf(b.x); o[5] = f2bf(b.y); o[6] = f2bf(b.z); o[7] = f2bf(b.w);
    *(bf16x8*)(d + (size_t)off * 8) = o;
}

// ---------------------------------------------------------------------------
// bf16 MFMA GEMM (NT), 64x64 tile, BK=64, 256 thr (2x2 waves, 32x32 each),
// double-buffered LDS, swizzled global_load_lds. Grid = (M/64, N/64):
// 1024+ blocks -> 4-5 blocks/CU for cross-block latency hiding.
// FLAGS: 1=f32 out, 2=bf16 out, 4=relu, 8=qscale(first 256 cols).
// ---------------------------------------------------------------------------
#define GSTAGE64(buf, kb)                                                    \
    {                                                                        \
        _Pragma("unroll")                                                    \
        for (int j = 0; j < 2; j++) {                                        \
            const int slot = w * 128 + j * 64 + l;                           \
            const int row = slot >> 3, c = slot & 7;                         \
            const int sw = (c ^ (row & 7)) << 3;                             \
            gl_lds16(A  + (size_t)(m0 + row) * K + (kb) + sw,                \
                     &Al[buf][(w * 128 + j * 64) * 8]);                      \
            gl_lds16(Bw + (size_t)(n0 + row) * K + (kb) + sw,                \
                     &Bl[buf][(w * 128 + j * 64) * 8]);                      \
        }                                                                    \
    }

template<int FLAGS>
__global__ __launch_bounds__(256) void gemm_bf16(const short* __restrict__ A,
                                                 const short* __restrict__ Bw,
                                                 const float* __restrict__ bias,
                                                 float* __restrict__ Cf,
                                                 short* __restrict__ Cb,
                                                 int M, int Nn, int K)
{
    __shared__ short Al[2][64 * 64];
    __shared__ short Bl[2][64 * 64];
    const int t = threadIdx.x, w = t >> 6, l = t & 63;
    const int lg = l >> 4, lr = l & 15;
    const int wm = w >> 1, wn = w & 1;
    const int m0 = blockIdx.x * 64, n0 = blockIdx.y * 64;

    f32x4 acc[2][2] = {};

    GSTAGE64(0, 0);
    __syncthreads();
    int cur = 0;
    for (int kb = 64; kb < K + 64; kb += 64) {
        if (kb < K) GSTAGE64(cur ^ 1, kb);
        #pragma unroll
        for (int ks = 0; ks < 2; ks++) {
            bf16x8 af[2], bfr[2];
            #pragma unroll
            for (int i = 0; i < 2; i++) {
                const int ar = wm * 32 + i * 16 + lr;
                af[i]  = *(const bf16x8*)&Al[cur][ar * 64 + (((lg + ks * 4) ^ (ar & 7)) << 3)];
                const int br = wn * 32 + i * 16 + lr;
                bfr[i] = *(const bf16x8*)&Bl[cur][br * 64 + (((lg + ks * 4) ^ (br & 7)) << 3)];
            }
            #pragma unroll
            for (int mi = 0; mi < 2; mi++)
                #pragma unroll
                for (int ni = 0; ni < 2; ni++)
                    acc[mi][ni] = __builtin_amdgcn_mfma_f32_16x16x32_bf16(af[mi], bfr[ni],
                                                                          acc[mi][ni], 0, 0, 0);
        }
        __syncthreads();
        cur ^= 1;
    }

    #pragma unroll
    for (int ni = 0; ni < 2; ni++) {
        const int n = n0 + wn * 32 + ni * 16 + lr;
        const float bv = bias[n];
        const float qs = ((FLAGS & 8) && n < 256) ? 0.17677669529663687f : 1.0f;
        #pragma unroll
        for (int mi = 0; mi < 2; mi++) {
            #pragma unroll
            for (int r = 0; r < 4; r++) {
                const int m = m0 + wm * 32 + mi * 16 + 4 * lg + r;
                float v = (acc[mi][ni][r] + bv) * qs;
                if (FLAGS & 4) v = fmaxf(v, 0.f);
                if (FLAGS & 1) Cf[(size_t)m * Nn + n] = v;
                if (FLAGS & 2) Cb[(size_t)m * Nn + n] = f2bf(v);
            }
        }
    }
}

// ---------------------------------------------------------------------------
// BatchNorm stats, two-stage deterministic (transposed partials).
// ---------------------------------------------------------------------------
__global__ __launch_bounds__(256) void bn_partial(const float* __restrict__ Y,
                                                  float* __restrict__ part)
{
    const int t = threadIdx.x, blk = blockIdx.x;
    float s = 0.f, sq = 0.f;
    const float* p = Y + (size_t)blk * 256 * 256 + t;
    for (int r = 0; r < 256; r++) {
        float v = p[(size_t)r * 256];
        s += v; sq += v * v;
    }
    part[t * 64 + blk]         = s;
    part[16384 + t * 64 + blk] = sq;
}

__global__ __launch_bounds__(256) void bn_finalize(const float* __restrict__ part,
                                                   const float* __restrict__ g,
                                                   const float* __restrict__ b,
                                                   float* __restrict__ sc)
{
    const int t = threadIdx.x;
    float s = 0.f, sq = 0.f;
    #pragma unroll
    for (int i = 0; i < 16; i++) {
        const float4 a = *(const float4*)&part[t * 64 + i * 4];
        const float4 q = *(const float4*)&part[16384 + t * 64 + i * 4];
        s  += (a.x + a.y) + (a.z + a.w);
        sq += (q.x + q.y) + (q.z + q.w);
    }
    const float mean = s * (1.f / (float)ROWS);
    const float var  = sq * (1.f / (float)ROWS) - mean * mean;
    const float k    = g[t] * rsqrtf(var + EPS_);
    sc[t]       = k;
    sc[256 + t] = b[t] - mean * k;
}

__global__ __launch_bounds__(256) void bn_apply_leaky(const float* __restrict__ Y,
                                                      const float* __restrict__ sc,
                                                      float* __restrict__ O)
{
    const int idx = blockIdx.x * 256 + threadIdx.x;
    const int c4  = (idx & 63) * 4;
    const float4 v  = *(const float4*)&Y[(size_t)idx * 4];
    const float4 k  = *(const float4*)&sc[c4];
    const float4 sh = *(const float4*)&sc[256 + c4];
    float4 o;
    o.x = fmaf(v.x, k.x, sh.x); o.x = o.x >= 0.f ? o.x : 0.01f * o.x;
    o.y = fmaf(v.y, k.y, sh.y); o.y = o.y >= 0.f ? o.y : 0.01f * o.y;
    o.z = fmaf(v.z, k.z, sh.z); o.z = o.z >= 0.f ? o.z : 0.01f * o.z;
    o.w = fmaf(v.w, k.w, sh.w); o.w = o.w >= 0.f ? o.w : 0.01f * o.w;
    *(float4*)&O[(size_t)idx * 4] = o;
}

// fused: h = leaky(bn(Y)) + deg_emb[deg]; writes h (f32) + hb (bf16)
__global__ __launch_bounds__(256) void bn_deg(const float* __restrict__ Y,
                                              const float* __restrict__ sc,
                                              const int* __restrict__ deg,
                                              const float* __restrict__ emb,
                                              float* __restrict__ h,
                                              short* __restrict__ hb)
{
    const int idx = blockIdx.x * 256 + threadIdx.x;
    const int row = idx >> 6;
    const int c4  = (idx & 63) * 4;
    const float4 v  = *(const float4*)&Y[(size_t)idx * 4];
    const float4 k  = *(const float4*)&sc[c4];
    const float4 sh = *(const float4*)&sc[256 + c4];
    const int d = deg[row];
    const float4 e = *(const float4*)&emb[(size_t)d * 256 + c4];
    float4 o;
    o.x = fmaf(v.x, k.x, sh.x); o.x = (o.x >= 0.f ? o.x : 0.01f * o.x) + e.x;
    o.y = fmaf(v.y, k.y, sh.y); o.y = (o.y >= 0.f ? o.y : 0.01f * o.y) + e.y;
    o.z = fmaf(v.z, k.z, sh.z); o.z = (o.z >= 0.f ? o.z : 0.01f * o.z) + e.z;
    o.w = fmaf(v.w, k.w, sh.w); o.w = (o.w >= 0.f ? o.w : 0.01f * o.w) + e.w;
    *(float4*)&h[(size_t)idx * 4] = o;
    short4 s4; s4.x = f2bf(o.x); s4.y = f2bf(o.y); s4.z = f2bf(o.z); s4.w = f2bf(o.w);
    *(short4*)&hb[(size_t)idx * 4] = s4;
}

// ---------------------------------------------------------------------------
// Degree: 256 blocks (32 b x 8 col-groups), 4 row-groups + LDS reduce.
// ---------------------------------------------------------------------------
__global__ __launch_bounds__(256) void deg_kernel(const int* __restrict__ adj,
                                                  int* __restrict__ deg)
{
    __shared__ int sm[4][64];
    const int b = blockIdx.x, j0 = blockIdx.y * 64;
    const int tg = threadIdx.x >> 6, lane = threadIdx.x & 63;
    const int* p = adj + (size_t)b * N_ * N_ + j0 + lane;
    int c = 0;
    #pragma unroll 4
    for (int i = tg; i < N_; i += 4) c += (p[(size_t)i * N_] != 0);
    sm[tg][lane] = c;
    __syncthreads();
    if (threadIdx.x < 64)
        deg[b * N_ + j0 + threadIdx.x] =
            sm[0][threadIdx.x] + sm[1][threadIdx.x] + sm[2][threadIdx.x] + sm[3][threadIdx.x];
}

// ---------------------------------------------------------------------------
// Residual + LayerNorm, writes h (f32) and hb (bf16)
// ---------------------------------------------------------------------------
__global__ __launch_bounds__(256) void add_ln2(float* __restrict__ h,
                                               short* __restrict__ hb,
                                               const float* __restrict__ p,
                                               const float* __restrict__ g,
                                               const float* __restrict__ be)
{
    const int wv = threadIdx.x >> 6, ln = threadIdx.x & 63;
    const size_t row  = (size_t)blockIdx.x * 4 + wv;
    const size_t base = row * 256 + ln * 4;
    const float4 a = *(const float4*)&h[base];
    const float4 q = *(const float4*)&p[base];
    const float v0 = a.x + q.x, v1 = a.y + q.y, v2 = a.z + q.z, v3 = a.w + q.w;
    float s  = v0 + v1 + v2 + v3;
    float sq = v0 * v0 + v1 * v1 + v2 * v2 + v3 * v3;
    #pragma unroll
    for (int m = 1; m < 64; m <<= 1) {
        s  += __shfl_xor(s,  m, 64);
        sq += __shfl_xor(sq, m, 64);
    }
    const float mean = s * (1.f / 256.f);
    const float var  = sq * (1.f / 256.f) - mean * mean;
    const float r    = rsqrtf(var + EPS_);
    const float4 gg = *(const float4*)&g[ln * 4];
    const float4 bb = *(const float4*)&be[ln * 4];
    float4 o;
    o.x = (v0 - mean) * r * gg.x + bb.x;
    o.y = (v1 - mean) * r * gg.y + bb.y;
    o.z = (v2 - mean) * r * gg.z + bb.z;
    o.w = (v3 - mean) * r * gg.w + bb.w;
    *(float4*)&h[base] = o;
    short4 sb; sb.x = f2bf(o.x); sb.y = f2bf(o.y); sb.z = f2bf(o.z); sb.w = f2bf(o.w);
    *(short4*)&hb[base] = sb;
}

// ---------------------------------------------------------------------------
// MFMA bf16 flash attention (swapped-operand). This round:
// - QK^T computed with C=0; spd/semb bias ADDED AFTER the MFMA -> the int4
//   spd loads (issued at phase top) overlap ds_reads + 16 MFMAs instead of
//   serializing as the C operand.
// - P-pack via v_cvt_pk_bf16_f32 (16 ops/qt, was 128 scalar f2bf ops).
// - max / ps reductions tree-shaped (depth 5, was 32-op serial chains).
// ---------------------------------------------------------------------------
#define KST 40    // K LDS row stride (bf16)
#define VST 136   // Vt LDS row stride (+32-short offset per 16-row half)
#define PST 136   // P LDS row stride

__global__ __launch_bounds__(256) void attn_mfma(const short* __restrict__ qkv,
                                                 const int* __restrict__ spd,
                                                 const float* __restrict__ semb,
                                                 short* __restrict__ out)
{
    __shared__ short Kl[128 * KST];
    __shared__ short Vl[32 * VST + 64];
    __shared__ short Pl[4][16 * PST];
    __shared__ float sembL[128];

    const int t  = threadIdx.x, w = t >> 6, l = t & 63;
    const int lg = l >> 4, lr = l & 15;

    const int s   = ((blockIdx.x & 7) << 7) + (blockIdx.x >> 3);
    const int bs  = s >> 5, ie = (s >> 2) & 7, qb = s & 3;
    const int b   = (ie * 32 + bs) >> 3, hd = (ie * 32 + bs) & 7;
    const int q0  = qb * 128 + w * 32;

    if (t < 100) sembL[t] = semb[t * 8 + ie];

    bf16x8 qf[2];
    #pragma unroll
    for (int qt = 0; qt < 2; qt++)
        qf[qt] = *(const bf16x8*)&qkv[((size_t)b * N_ + q0 + qt * 16 + lr) * 768 + hd * 32 + lg * 8];

    f32x4 oacc[2][2] = {};
    float mrun[2] = {-INFINITY, -INFINITY}, srun[2] = {0.f, 0.f};

    const int sr = t >> 1, shf = (t & 1) << 4;
    const int vofs = (t & 1) * 32;
    const short* kgBase = qkv + ((size_t)b * N_ + sr) * 768 + 256 + hd * 32 + shf;

    // prologue: stage tile 0
    bf16x8 nk0 = *(const bf16x8*)(kgBase);
    bf16x8 nk1 = *(const bf16x8*)(kgBase + 8);
    bf16x8 nv0 = *(const bf16x8*)(kgBase + 256);
    bf16x8 nv1 = *(const bf16x8*)(kgBase + 264);
    *(bf16x8*)&Kl[sr * KST + shf]     = nk0;
    *(bf16x8*)&Kl[sr * KST + shf + 8] = nk1;
    #pragma unroll
    for (int i = 0; i < 8; i++) {
        Vl[(shf + i)     * VST + vofs + sr] = nv0[i];
        Vl[(shf + 8 + i) * VST + vofs + sr] = nv1[i];
    }
    __syncthreads();

    const f32x4 zc = {0.f, 0.f, 0.f, 0.f};

    for (int ti = 0; ti < 4; ti++) {
        const int k0 = ti * 128;

        // qt0 spd loads first: land under ds_reads + QK0 MFMAs
        int4 sv0[8];
        {
            const int4* sp0 = (const int4*)(spd + ((size_t)bs * N_ + q0 + lr) * N_ + k0);
            #pragma unroll
            for (int ct = 0; ct < 8; ct++) sv0[ct] = sp0[ct * 4 + lg];
        }

        bf16x8 kfr[8];
        #pragma unroll
        for (int ct = 0; ct < 8; ct++)
            kfr[ct] = *(const bf16x8*)&Kl[(ct * 16 + lr) * KST + lg * 8];

        // QK0 with C=0
        f32x4 sA[8];
        #pragma unroll
        for (int ct = 0; ct < 8; ct++)
            sA[ct] = __builtin_amdgcn_mfma_f32_16x16x32_bf16(kfr[ct], qf[0], zc, 0, 0, 0);

        // qt1 spd loads + next-tile K/V prefetch + vfr reads (all overlap qt0 tail)
        int4 sv1[8];
        {
            const int4* sp1 = (const int4*)(spd + ((size_t)bs * N_ + q0 + 16 + lr) * N_ + k0);
            #pragma unroll
            for (int ct = 0; ct < 8; ct++) sv1[ct] = sp1[ct * 4 + lg];
        }
        const short* kgN = kgBase + (size_t)(((ti + 1) & 3) * 128) * 768;
        nk0 = *(const bf16x8*)(kgN);
        nk1 = *(const bf16x8*)(kgN + 8);
        nv0 = *(const bf16x8*)(kgN + 256);
        nv1 = *(const bf16x8*)(kgN + 264);
        bf16x8 vfr[4][2];
        #pragma unroll
        for (int kt = 0; kt < 4; kt++)
            #pragma unroll
            for (int c2 = 0; c2 < 2; c2++)
                vfr[kt][c2] = *(const bf16x8*)&Vl[(c2 * 16 + lr) * VST + c2 * 32 + kt * 32 + lg * 8];

        #pragma unroll
        for (int qt = 0; qt < 2; qt++) {
            if (qt == 1) {   // QK1 with C=0
                #pragma unroll
                for (int ct = 0; ct < 8; ct++)
                    sA[ct] = __builtin_amdgcn_mfma_f32_16x16x32_bf16(kfr[ct], qf[1], zc, 0, 0, 0);
            }
            // bias add (consume sv)
            #pragma unroll
            for (int ct = 0; ct < 8; ct++) {
                const int4 sv = (qt == 0) ? sv0[ct] : sv1[ct];
                sA[ct][0] += (sv.x < 0) ? -1.0f : sembL[sv.x];
                sA[ct][1] += (sv.y < 0) ? -1.0f : sembL[sv.y];
                sA[ct][2] += (sv.z < 0) ? -1.0f : sembL[sv.z];
                sA[ct][3] += (sv.w < 0) ? -1.0f : sembL[sv.w];
            }
            // tree max over 32
            float mx[8];
            #pragma unroll
            for (int ct = 0; ct < 8; ct++)
                mx[ct] = fmaxf(fmaxf(sA[ct][0], sA[ct][1]), fmaxf(sA[ct][2], sA[ct][3]));
            float m = fmaxf(fmaxf(fmaxf(mx[0], mx[1]), fmaxf(mx[2], mx[3])),
                            fmaxf(fmaxf(mx[4], mx[5]), fmaxf(mx[6], mx[7])));
            m = fmaxf(m, __shfl_xor(m, 16, 64));
            m = fmaxf(m, __shfl_xor(m, 32, 64));
            const float mnew  = fmaxf(mrun[qt], m);
            const float alpha = __expf(mrun[qt] - mnew);
            mrun[qt] = mnew;

            // exp + pack (cvt_pk) + tree sum
            float ps4[8];
            #pragma unroll
            for (int ct = 0; ct < 8; ct++) {
                const float e0 = __expf(sA[ct][0] - mnew);
                const float e1 = __expf(sA[ct][1] - mnew);
                const float e2 = __expf(sA[ct][2] - mnew);
                const float e3 = __expf(sA[ct][3] - mnew);
                ps4[ct] = (e0 + e1) + (e2 + e3);
                uint2 pk; pk.x = cvtpk(e0, e1); pk.y = cvtpk(e2, e3);
                *(uint2*)&Pl[w][lr * PST + ct * 16 + 4 * lg] = pk;
            }
            float ps = (((ps4[0] + ps4[1]) + (ps4[2] + ps4[3])) +
                        ((ps4[4] + ps4[5]) + (ps4[6] + ps4[7])));
            ps += __shfl_xor(ps, 16, 64);
            ps += __shfl_xor(ps, 32, 64);
            srun[qt] = srun[qt] * alpha + ps;
            oacc[qt][0] *= alpha;
            oacc[qt][1] *= alpha;

            #pragma unroll
            for (int kt = 0; kt < 4; kt++) {
                const bf16x8 pa = *(const bf16x8*)&Pl[w][lr * PST + kt * 32 + lg * 8];
                #pragma unroll
                for (int c2 = 0; c2 < 2; c2++)
                    oacc[qt][c2] = __builtin_amdgcn_mfma_f32_16x16x32_bf16(vfr[kt][c2], pa,
                                                                           oacc[qt][c2], 0, 0, 0);
            }
        }

        if (ti < 3) {
            __syncthreads();
            *(bf16x8*)&Kl[sr * KST + shf]     = nk0;
            *(bf16x8*)&Kl[sr * KST + shf + 8] = nk1;
            #pragma unroll
            for (int i = 0; i < 8; i++) {
                Vl[(shf + i)     * VST + vofs + sr] = nv0[i];
                Vl[(shf + 8 + i) * VST + vofs + sr] = nv1[i];
            }
            __syncthreads();
        }
    }

    #pragma unroll
    for (int qt = 0; qt < 2; qt++) {
        const float inv = 1.f / srun[qt];
        #pragma unroll
        for (int c2 = 0; c2 < 2; c2++) {
            uint2 o2;
            o2.x = cvtpk(oacc[qt][c2][0] * inv, oacc[qt][c2][1] * inv);
            o2.y = cvtpk(oacc[qt][c2][2] * inv, oacc[qt][c2][3] * inv);
            *(uint2*)&out[((size_t)b * N_ + q0 + qt * 16 + lr) * 256 + hd * 32 + c2 * 16 + 4 * lg] = o2;
        }
    }
}

// ---------------------------------------------------------------------------
extern "C" void kernel_launch(void* const* d_in, const int* in_sizes, int n_in,
                              void* d_out, int out_size, void* d_ws, size_t ws_size,
                              hipStream_t stream)
{
    const float* x    = (const float*)d_in[0];
    const int*   adj  = (const int*)  d_in[1];
    const int*   spd  = (const int*)  d_in[2];
    const float* Wf   = (const float*)d_in[3];
    const float* bf   = (const float*)d_in[4];
    const float* bn1g = (const float*)d_in[5];
    const float* bn1b = (const float*)d_in[6];
    const float* degE = (const float*)d_in[7];
    const float* semb = (const float*)d_in[8];
    const float* Wqkv = (const float*)d_in[9];
    const float* bqkv = (const float*)d_in[10];
    const float* Wo   = (const float*)d_in[11];
    const float* bo   = (const float*)d_in[12];
    const float* ln1g = (const float*)d_in[13];
    const float* ln1b = (const float*)d_in[14];
    const float* W1   = (const float*)d_in[15];
    const float* b1   = (const float*)d_in[16];
    const float* W2   = (const float*)d_in[17];
    const float* b2   = (const float*)d_in[18];
    const float* ln2g = (const float*)d_in[19];
    const float* ln2b = (const float*)d_in[20];
    const float* Win  = (const float*)d_in[21];
    const float* bin  = (const float*)d_in[22];
    const float* bn2g = (const float*)d_in[23];
    const float* bn2b = (const float*)d_in[24];

    char* p = (char*)d_ws;
    float* h    = (float*)p;  p += (size_t)ROWS * 256 * 4;
    float* t3   = (float*)p;  p += (size_t)ROWS * 256 * 4;
    char*  shr  = p;          p += (size_t)ROWS * 768 * 2;   // t1(f32) / qkvb(bf16)
    float* t1   = (float*)shr;
    short* qkvb = (short*)shr;
    short* hb   = (short*)p;  p += (size_t)ROWS * 256 * 2;
    short* t2b  = (short*)p;  p += (size_t)ROWS * 256 * 2;
    short* xb   = (short*)p;  p += (size_t)ROWS * 256 * 2;
    short* wb   = (short*)p;  p += (size_t)917504 * 2;
    int*   deg  = (int*)p;    p += (size_t)ROWS * 4;
    float* bnp  = (float*)p;  p += 64 * 512 * 4;
    float* bnf  = (float*)p;

    const short* wfb = wb;
    const short* wqb = wb + 65536;
    const short* wob = wb + 458752;
    const short* w1b = wb + 589824;
    const short* w2b = wb + 720896;
    const short* wib = wb + 851968;

    const dim3 blk(256);
    const dim3 g256(ROWS / 64, 4);     // 1024 blocks
    const dim3 g768(ROWS / 64, 12);    // 3072 blocks

    cvt_all<<<2496, blk, 0, stream>>>(x, Wf, Wqkv, Wo, W1, W2, Win, xb, wb);
    deg_kernel<<<dim3(B_, 8), blk, 0, stream>>>(adj, deg);

    // 1. lin_first + BN + leaky + degree add (fused apply)
    gemm_bf16<1><<<g256, blk, 0, stream>>>(xb, wfb, bf, t1, nullptr, ROWS, 256, 256);
    bn_partial <<<64, blk, 0, stream>>>(t1, bnp);
    bn_finalize<<<1,  blk, 0, stream>>>(bnp, bn1g, bn1b, bnf);
    bn_deg<<<ROWS * 256 / 4 / 256, blk, 0, stream>>>(t1, bnf, deg, degE, h, hb);

    // 2. transformer layers
    for (int l = 0; l < L_; l++) {
        gemm_bf16<2 | 8><<<g768, blk, 0, stream>>>(hb, wqb + (size_t)l * 768 * 256,
                                                   bqkv + l * 768, nullptr, qkvb, ROWS, 768, 256);
        attn_mfma<<<1024, blk, 0, stream>>>(qkvb, spd, semb, t2b);
        gemm_bf16<1><<<g256, blk, 0, stream>>>(t2b, wob + (size_t)l * 256 * 256,
                                               bo + l * 256, t3, nullptr, ROWS, 256, 256);
        add_ln2<<<ROWS / 4, blk, 0, stream>>>(h, hb, t3, ln1g + l * 256, ln1b + l * 256);
        gemm_bf16<2 | 4><<<g256, blk, 0, stream>>>(hb, w1b + (size_t)l * 256 * 256,
                                                   b1 + l * 256, nullptr, t2b, ROWS, 256, 256);
        gemm_bf16<1><<<g256, blk, 0, stream>>>(t2b, w2b + (size_t)l * 256 * 256,
                                               b2 + l * 256, t3, nullptr, ROWS, 256, 256);
        add_ln2<<<ROWS / 4, blk, 0, stream>>>(h, hb, t3, ln2g + l * 256, ln2b + l * 256);
    }

    // 3. lin_in + BN + leaky -> out
    gemm_bf16<1><<<g256, blk, 0, stream>>>(hb, wib, bin, t1, nullptr, ROWS, 256, 256);
    bn_partial <<<64, blk, 0, stream>>>(t1, bnp);
    bn_finalize<<<1,  blk, 0, stream>>>(bnp, bn2g, bn2b, bnf);
    bn_apply_leaky<<<ROWS * 256 / 4 / 256, blk, 0, stream>>>(t1, bnf, (float*)d_out);
}